// Round 10
// baseline (220.003 us; speedup 1.0000x reference)
//
#include <hip/hip_runtime.h>
#include <math.h>

#define N_PTS 16384
#define K_NBR 16
#define H_DIM 64
#define CAP   48              // per-query/per-part buffer; 4*16*CAP*8+64 <= 26624
#define NBLK  (N_PTS / 16)    // 1024 column-blocks of 16 candidates
#define HBLK  (NBLK / 2)      // 512 col-blocks per half
#define PBLK  (HBLK / 4)      // 128 col-blocks per wave-part

typedef unsigned long long u64;
typedef unsigned short u16;
typedef float v2f   __attribute__((ext_vector_type(2)));
typedef float f32x4 __attribute__((ext_vector_type(4)));
typedef short bf16x8 __attribute__((ext_vector_type(8)));

// key = (order-preserving float bits, ~idx): sorts by value desc then idx asc
__device__ __forceinline__ u64 mkkey(unsigned vbits, unsigned idx) {
    unsigned of = vbits ^ (unsigned)(((int)vbits >> 31) | 0x80000000);
    return ((u64)of << 32) | (unsigned)(~idx);
}
__device__ __forceinline__ unsigned keyidx(u64 k) { return ~(unsigned)k; }

__device__ __forceinline__ float readlane_f(float v, int l) {
    return __uint_as_float(__builtin_amdgcn_readlane(__float_as_uint(v), l));
}

// order-preserving float<->uint (tau stored in LDS as monotone uint)
__device__ __forceinline__ unsigned ofsbits(float f) {
    unsigned b = __float_as_uint(f);
    return b ^ ((unsigned)((int)b >> 31) | 0x80000000u);
}
__device__ __forceinline__ float inv_ofs(unsigned u) {
    return __uint_as_float(u ^ (~(unsigned)((int)u >> 31) | 0x80000000u));
}

// bf16 RNE helpers (identical arithmetic in prep and knn query-side)
__device__ __forceinline__ u16 f2bf(float f) {
    unsigned u = __float_as_uint(f);
    return (u16)((u + 0x7FFFu + ((u >> 16) & 1u)) >> 16);
}
__device__ __forceinline__ float bf2f(u16 b) {
    return __uint_as_float(((unsigned)b) << 16);
}

// 64-lane bitonic ascending sort, float
__device__ __forceinline__ float wave_sort_f32(float v, int lane) {
#pragma unroll
    for (int k = 2; k <= 64; k <<= 1) {
#pragma unroll
        for (int j = k >> 1; j > 0; j >>= 1) {
            float o = __shfl_xor(v, j, 64);
            bool keep_min = (((lane & k) == 0) == ((lane & j) == 0));
            v = keep_min ? fminf(v, o) : fmaxf(v, o);
        }
    }
    return v;
}
// 64-lane bitonic ascending sort, u64 keys
__device__ __forceinline__ u64 wave_sort_u64(u64 v, int lane) {
#pragma unroll
    for (int k = 2; k <= 64; k <<= 1) {
#pragma unroll
        for (int j = k >> 1; j > 0; j >>= 1) {
            u64 o = __shfl_xor((unsigned long long)v, j, 64);
            bool keep_min = (((lane & k) == 0) == ((lane & j) == 0));
            u64 mn = (v < o) ? v : o;
            u64 mx = (v < o) ? o : v;
            v = keep_min ? mn : mx;
        }
    }
    return v;
}
// two independent 32-lane ascending sorts (halves of the wave); all shfl
// distances <= 16 so lanes never cross the 32-boundary.
__device__ __forceinline__ u64 half32_sort_u64(u64 v, int lane) {
    const int l = lane & 31;
#pragma unroll
    for (int k = 2; k <= 32; k <<= 1) {
#pragma unroll
        for (int j = k >> 1; j > 0; j >>= 1) {
            u64 o = __shfl_xor((unsigned long long)v, j, 64);
            bool keep_min = (((l & k) == 0) == ((l & j) == 0));
            u64 mn = (v < o) ? v : o;
            u64 mx = (v < o) ? o : v;
            v = keep_min ? mn : mx;
        }
    }
    return v;
}

// raise tau to 16th-largest of per-lane max VALUES, drop entries below.
// Exact invariant: tau <= 16th-largest value in buffer (>= 16 entries >= tau
// retained; boundary ties kept).
struct CompRes { int nc; float tau; };
__device__ __attribute__((noinline)) CompRes wave_compact(uint2* buf, int cnt,
                                                          int lane) {
    float lm = -INFINITY;
    for (int s = lane; s < cnt; s += 64)
        lm = fmaxf(lm, __uint_as_float(buf[s].x));
    const float tv = readlane_f(wave_sort_f32(lm, lane), 48);
    int nc = 0;
    for (int s0 = 0; s0 < cnt; s0 += 64) {
        const int s = s0 + lane;
        uint2 e = make_uint2(0u, 0u);
        bool keep = false;
        if (s < cnt) { e = buf[s]; keep = (__uint_as_float(e.x) >= tv); }
        const u64 km = __ballot(keep);
        if (keep) {
            int pfx = (int)__popcll(km & ((1ull << lane) - 1));
            buf[nc + pfx] = e;   // write idx <= read idx: safe
        }
        nc += (int)__popcll(km);
    }
    CompRes r; r.nc = nc; r.tau = tv;
    return r;
}

// ---------------- prep: fragment array for bf16x3-split MFMA ---------------
// Score(i,j) = 2*xi.xj - ||xj||^2  (row term -||xi||^2 is rank-invariant).
// K-slot map (k = c + 4p, c=0..3): pairs p:(sa,sb) = (0,0)(0,1)(1,0)(0,2)
// (2,0)(1,1)  [hh,hm,mh,hl,lh,mm of split3]; k=24..26: query-side 1.0,
// cand-side split3(-xx); k=27..31: 0.  Dropped terms (ml,lm,ll) ~2^-27 rel.
__global__ __launch_bounds__(256) void prep_kernel(const float4* __restrict__ x4,
                                                   u16* __restrict__ bf) {
    const int i = blockIdx.x * 256 + threadIdx.x;
    const float4 v = x4[i];
    float xx;
    {
#pragma clang fp contract(off)
        float s0 = v.x * v.x, s1 = v.y * v.y, s2 = v.z * v.z, s3 = v.w * v.w;
        xx = ((s0 + s1) + s2) + s3;
    }
    float c[4] = {v.x, v.y, v.z, v.w};
    u16 H[4], M[4], L[4];
#pragma unroll
    for (int q = 0; q < 4; ++q) {
        float f = c[q];
        u16 h = f2bf(f);            float fh = bf2f(h);
        u16 m = f2bf(f - fh);       float fm = bf2f(m);
        u16 l = f2bf(f - fh - fm);
        H[q] = h; M[q] = m; L[q] = l;
    }
    const float nx = -xx;
    u16 X0 = f2bf(nx);              float x0f = bf2f(X0);
    u16 X1 = f2bf(nx - x0f);        float x1f = bf2f(X1);
    u16 X2 = f2bf(nx - x0f - x1f);
    u16 o[32];
#pragma unroll
    for (int q = 0; q < 4; ++q) {
        o[q]      = H[q];  // p0: sb=hi
        o[4 + q]  = M[q];  // p1: sb=mid
        o[8 + q]  = H[q];  // p2: sb=hi
        o[12 + q] = L[q];  // p3: sb=lo
        o[16 + q] = H[q];  // p4: sb=hi
        o[20 + q] = M[q];  // p5: sb=mid
    }
    o[24] = X0; o[25] = X1; o[26] = X2;
    o[27] = 0; o[28] = 0; o[29] = 0; o[30] = 0; o[31] = 0;
    uint4* dst = (uint4*)(bf + (size_t)i * 32);
#pragma unroll
    for (int q2 = 0; q2 < 4; ++q2) {
        uint4 w;
        w.x = (unsigned)o[q2 * 8 + 0] | ((unsigned)o[q2 * 8 + 1] << 16);
        w.y = (unsigned)o[q2 * 8 + 2] | ((unsigned)o[q2 * 8 + 3] << 16);
        w.z = (unsigned)o[q2 * 8 + 4] | ((unsigned)o[q2 * 8 + 5] << 16);
        w.w = (unsigned)o[q2 * 8 + 6] | ((unsigned)o[q2 * 8 + 7] << 16);
        dst[q2] = w;
    }
}

// ---------------- kNN: two-phase, COLUMN-HALVED grid for occupancy ---------
// R8/R9 post-mortem: latency-cover via registers always spills (unified
// VGPR+AGPR budget; working set ~52 arch + ~24 acc). So raise TLP via
// BLOCKS: grid 2048 = (query-group, half). Each block runs the exact R7
// per-wave shell (2-deep, 52 VGPR proven) on its half's columns. CAP 48
// (tau-tight survivors/part ~8) -> LDS 24640 B -> 6 blk/CU at (256,6)
// (VGPR cap ~85 >= ~76 needed: no spill). Each half emits an exact half
// top-16 per query (tau <= p16(half) via 64 disjoint-class maxima); keys
// stored as full-precision (valbits u32, idx u16); mlp merges 32->16.
__global__ __launch_bounds__(256, 6) void knn_kernel(
        const float4* __restrict__ x4,
        const u16* __restrict__ bfrag,
        unsigned* __restrict__ vals,
        u16* __restrict__ idxs) {
    __shared__ __align__(16) uint2 buf[4][16][CAP];   // 24576 B
    __shared__ unsigned tau_sh[16];                   // +64 B = 24640 B
    const int lane = threadIdx.x & 63;
    const int wave = threadIdx.x >> 6;
    const int q    = lane & 15;
    const int g    = lane >> 4;
    const int qgrp = blockIdx.x >> 1;
    const int half = blockIdx.x & 1;
    const int rowbase = qgrp * 16;
    const int pblk = half * HBLK + wave * PBLK;   // part's first 16-col block

    // ---- query fragment (B operand): query = q, k-chunk = g ----
    const float4 xi = x4[rowbase + q];
    u16 Ha[4], Ma[4], La[4];
    {
        float yy[4] = {2.f * xi.x, 2.f * xi.y, 2.f * xi.z, 2.f * xi.w};
#pragma unroll
        for (int c = 0; c < 4; ++c) {
            u16 h = f2bf(yy[c]);             float fh = bf2f(h);
            u16 m = f2bf(yy[c] - fh);        float fm = bf2f(m);
            u16 l = f2bf(yy[c] - fh - fm);
            Ha[c] = h; Ma[c] = m; La[c] = l;
        }
    }
    bf16x8 qfrag;
    {
        const u16 ONEB = 0x3F80;  // bf16 1.0
#pragma unroll
        for (int c = 0; c < 4; ++c) {
            u16 lo, hi;
            if (g == 0)      { lo = Ha[c]; hi = Ha[c]; }  // p0:hi  p1:hi
            else if (g == 1) { lo = Ma[c]; hi = Ha[c]; }  // p2:mid p3:hi
            else if (g == 2) { lo = La[c]; hi = Ma[c]; }  // p4:lo  p5:mid
            else             { lo = (c < 3) ? ONEB : 0; hi = 0; }  // k24..26=1
            qfrag[c]     = (short)lo;
            qfrag[c + 4] = (short)hi;
        }
    }
    const f32x4 zacc = {0.f, 0.f, 0.f, 0.f};
    // candidate fragment (A operand): cand-in-block = lane&15, k-chunk = g
    const bf16x8* bp = (const bf16x8*)bfrag + (size_t)pblk * 64 + (q * 4 + g);

    // ================= Phase A: sampled class-maxima (stride-2 blocks) =====
    f32x4 mx = {-INFINITY, -INFINITY, -INFINITY, -INFINITY};
    {
        bf16x8 A0[4], A1[4];
#pragma unroll
        for (int i = 0; i < 4; ++i) A0[i] = bp[(2 * i) * 64];        // 0,2,4,6
#pragma unroll
        for (int i = 0; i < 4; ++i) A1[i] = bp[(8 + 2 * i) * 64];    // 8..14
        const bf16x8* pa = bp + 16 * 64;

#define PROCA(BUF) do {                                                      \
    _Pragma("unroll")                                                        \
    for (int i = 0; i < 4; ++i) {                                            \
        const f32x4 aa = __builtin_amdgcn_mfma_f32_16x16x32_bf16(            \
            BUF[i], qfrag, zacc, 0, 0, 0);                                   \
        mx[0] = fmaxf(mx[0], aa[0]); mx[1] = fmaxf(mx[1], aa[1]);            \
        mx[2] = fmaxf(mx[2], aa[2]); mx[3] = fmaxf(mx[3], aa[3]);            \
    }                                                                        \
} while (0)

        for (int it = 0; it < 7; ++it) {   // 7*8 + 8 = 64 sampled blocks
            PROCA(A0);
#pragma unroll
            for (int i = 0; i < 4; ++i) A0[i] = pa[(2 * i) * 64];
            PROCA(A1);
#pragma unroll
            for (int i = 0; i < 4; ++i) A1[i] = pa[(8 + 2 * i) * 64];
            pa += 16 * 64;
        }
        PROCA(A0);                         // sampled blocks 112..118
        PROCA(A1);                         // sampled blocks 120..126
#undef PROCA
    }

    // ---- combine: 64 class-maxima per query -> tau = 16th largest ----
    // (4 waves x 4 g x 4 reg disjoint classes within this half)
    {
        float* am = (float*)&buf[0][0][0];          // 4 KB scratch alias
        const int base = wave * 256 + q * 16 + g * 4;
        am[base + 0] = mx[0]; am[base + 1] = mx[1];
        am[base + 2] = mx[2]; am[base + 3] = mx[3];
        __syncthreads();
#pragma unroll
        for (int rr = 0; rr < 4; ++rr) {
            const int r = wave * 4 + rr;
            float v = am[(lane >> 4) * 256 + r * 16 + (lane & 15)];
            v = wave_sort_f32(v, lane);
            if (lane == 48) tau_sh[r] = ofsbits(v);  // 16th largest of 64
        }
        __syncthreads();
    }
    float tau = inv_ofs(tau_sh[q]);        // half-tight, fixed for Phase B

    unsigned cq = 0;                        // per-query count (lane-wise,
    uint2* bq = &buf[wave][q][0];           //  replicated across the 4 g-lanes)
    const unsigned gid4 = (unsigned)(g * 4);

// lean lane-wise insert; cold path compacts the overflowing queries
// (ballot/ctz-driven), raising their LOCAL taus.
#define INSERT4(AV, CB) do {                                                 \
    for (;;) {                                                               \
        const bool k0 = (AV)[0] >= tau, k1 = (AV)[1] >= tau;                 \
        const bool k2 = (AV)[2] >= tau, k3 = (AV)[3] >= tau;                 \
        const int cnt = (int)k0 + (int)k1 + (int)k2 + (int)k3;               \
        const int sa = __shfl_xor(cnt, 16, 64);                              \
        const int sb = __shfl_xor(cnt, 32, 64);                              \
        const int sc = __shfl_xor(sa, 32, 64);                               \
        const int tot = cnt + sa + sb + sc;                                  \
        const int pf  = ((g & 1) ? sa : 0) + ((g & 2) ? (sb + sc) : 0);      \
        const u64 ovm = __ballot(cq + (unsigned)tot > CAP);                  \
        if (__builtin_expect(ovm == 0, 1)) {                                 \
            unsigned slot = cq + (unsigned)pf;                               \
            if (k0) bq[slot++] = make_uint2(__float_as_uint((AV)[0]), (CB)); \
            if (k1) bq[slot++] = make_uint2(__float_as_uint((AV)[1]), (CB)+1);\
            if (k2) bq[slot++] = make_uint2(__float_as_uint((AV)[2]), (CB)+2);\
            if (k3) bq[slot++] = make_uint2(__float_as_uint((AV)[3]), (CB)+3);\
            cq += (unsigned)tot;                                             \
            break;                                                           \
        }                                                                    \
        u64 ov = ovm & 0xFFFFull;                                            \
        while (ov) {                                                         \
            const int r = (int)__builtin_ctzll(ov); ov &= ov - 1;            \
            const unsigned cr =                                              \
                (unsigned)__builtin_amdgcn_readlane((int)cq, r);             \
            CompRes res = wave_compact(&buf[wave][r][0], (int)cr, lane);     \
            if (q == r) { cq = (unsigned)res.nc;                             \
                          tau = fmaxf(tau, res.tau); }                       \
        }                                                                    \
    }                                                                        \
} while (0)

// one 16x16 block: MFMA -> 3-fmax gate -> rare insert
#define PROC4(BUF, TB) do {                                                  \
    f32x4 A4_[4];                                                            \
    _Pragma("unroll")                                                        \
    for (int i = 0; i < 4; ++i)                                              \
        A4_[i] = __builtin_amdgcn_mfma_f32_16x16x32_bf16(BUF[i], qfrag,      \
                                                         zacc, 0, 0, 0);     \
    _Pragma("unroll")                                                        \
    for (int i = 0; i < 4; ++i) {                                            \
        const f32x4 av = A4_[i];                                             \
        const float m4 = fmaxf(fmaxf(av[0], av[1]), fmaxf(av[2], av[3]));    \
        if (__ballot(m4 >= tau))                                             \
            INSERT4(av, (unsigned)(((TB) + i) * 16) + gid4);                 \
    }                                                                        \
} while (0)

    // ================= Phase B: full stream, fixed tau, 2-deep =============
    {
        bf16x8 B0[4], B1[4];
#pragma unroll
        for (int i = 0; i < 4; ++i) B0[i] = bp[i * 64];
#pragma unroll
        for (int i = 0; i < 4; ++i) B1[i] = bp[(4 + i) * 64];
        const bf16x8* pA = bp + 8 * 64;    // refill source for B0 (block t+8)
        const bf16x8* pB = bp + 12 * 64;   // refill source for B1 (block t+12)

        int t = 0;
        for (; t < PBLK - 8; t += 8) {
            PROC4(B0, pblk + t);
#pragma unroll
            for (int i = 0; i < 4; ++i) B0[i] = pA[i * 64];
            pA += 8 * 64;
            PROC4(B1, pblk + t + 4);
#pragma unroll
            for (int i = 0; i < 4; ++i) B1[i] = pB[i * 64];
            pB += 8 * 64;
        }
        PROC4(B0, pblk + t);               // blocks 120..123
        PROC4(B1, pblk + t + 4);           // blocks 124..127
    }
#undef PROC4
#undef INSERT4

    // ---- per-part finalize: park top-16 keys (c <= CAP=48 < 64 always) ----
#pragma unroll 1
    for (int r = 0; r < 16; ++r) {
        int c = __builtin_amdgcn_readlane((int)cq, r);
        uint2* br = &buf[wave][r][0];
        if (c <= 16) {                     // typical: park (merge re-sorts)
            if (lane < 16) {
                u64 key = 0;
                if (lane < c) { const uint2 e = br[lane]; key = mkkey(e.x, e.y); }
                *(u64*)&buf[wave][r][lane] = key;
            }
        } else {
            u64 key = 0;                   // sentinel < any real key
            if (lane < c) { const uint2 e = br[lane]; key = mkkey(e.x, e.y); }
            key = wave_sort_u64(key, lane);
            if (lane >= 48)
                *(u64*)&buf[wave][r][lane - 48] = key;  // top-16, slots 0..15
        }
    }

    // ---- in-block merge: 64 keys/query (4 parts x 16) -> half top-16 ----
    __syncthreads();
#pragma unroll
    for (int rr = 0; rr < 4; ++rr) {
        const int r2 = wave * 4 + rr;
        u64 key = *(const u64*)&buf[lane >> 4][r2][lane & 15];
        key = wave_sort_u64(key, lane);
        if (lane >= 48) {
            const int o = (rowbase + r2) * 32 + half * 16 + (lane - 48);
            vals[o] = (unsigned)(key >> 32);       // ofs-transformed value
            idxs[o] = (u16)keyidx(key);            // idx < 16384 fits u16
        }
    }
}

// ---------------- edge-feature MLP: 32->16 merge + gather + hoisted W2 -----
__global__ __launch_bounds__(256, 2) void mlp_kernel(
        const float4* __restrict__ x4,
        const unsigned* __restrict__ vals,
        const u16* __restrict__ idxs,
        const float4* __restrict__ W2f4,
        const float* __restrict__ W1,
        const float* __restrict__ b1,
        const float* __restrict__ b2,
        float* __restrict__ out) {
    __shared__ __align__(16) float4 w2s[16][64];     // 16 KB, h4-major
    __shared__ __align__(16) float  h1s[4][32][68];  // 34 KB, per-wave
    __shared__ __align__(16) float4 xjs[4][32];      // 2 KB, per-wave gather
    const int lane = threadIdx.x & 63;
    const int wave = threadIdx.x >> 6;
    const int kq   = lane >> 4;
    const int gp   = lane & 15;
    const int p0   = (blockIdx.x * 4 + wave) * 2;    // 2 points per wave

    for (int q = threadIdx.x; q < 1024; q += 256)
        w2s[q & 15][q >> 4] = W2f4[q];               // w2s[h4][g]
    __syncthreads();

    float w1r[8];
#pragma unroll
    for (int c = 0; c < 8; ++c) w1r[c] = W1[lane * 8 + c];
    const float b1r = b1[lane];
    float b2r[4];
#pragma unroll
    for (int gq = 0; gq < 4; ++gq) b2r[gq] = b2[gq * 16 + gp];

    // merge the two half-top-16s (exact: same value bits + idx tie-break as
    // the knn-side keys), then gather winners. Each 32-lane group handles
    // one point's 32 candidates; both halves have >=16 real keys so the
    // top-16 are always real.
    {
        const int pp = lane >> 5;                    // 0 or 1
        const int j  = lane & 31;
        const int o  = (p0 + pp) * 32 + j;
        u64 key = ((u64)vals[o] << 32) | (unsigned)(~(unsigned)idxs[o]);
        key = half32_sort_u64(key, lane);
        if ((lane & 31) >= 16) {
            const int nb = (int)((~(unsigned)key) & 0xFFFFu);
            xjs[wave][pp * 16 + ((lane & 31) - 16)] = x4[nb];
        }
    }
    // wave-private LDS + in-wave vmcnt/lgkmcnt ordering: no barrier

    // layer 1 for both points (lane = hidden feature h)
#pragma unroll
    for (int pp = 0; pp < 2; ++pp) {
        const float4 xi = x4[p0 + pp];
        float hb = b1r;
        hb = fmaf(w1r[4] - w1r[0], xi.x, hb);
        hb = fmaf(w1r[5] - w1r[1], xi.y, hb);
        hb = fmaf(w1r[6] - w1r[2], xi.z, hb);
        hb = fmaf(w1r[7] - w1r[3], xi.w, hb);
#pragma unroll
        for (int k = 0; k < K_NBR; ++k) {
            const float4 xj = xjs[wave][pp * 16 + k];
            float h = hb;
            h = fmaf(w1r[0], xj.x, h);
            h = fmaf(w1r[1], xj.y, h);
            h = fmaf(w1r[2], xj.z, h);
            h = fmaf(w1r[3], xj.w, h);
            h1s[wave][pp * 16 + k][lane] = fmaxf(h, 0.0f);
        }
    }

    // layer 2: acc[pp][kk][gq] (packed pairs over h), h4-outer, w4 hoisted
    v2f acc[2][4][4];
#pragma unroll
    for (int pp = 0; pp < 2; ++pp)
#pragma unroll
        for (int kk = 0; kk < 4; ++kk)
#pragma unroll
            for (int gq = 0; gq < 4; ++gq)
                acc[pp][kk][gq] = (v2f){b2r[gq], 0.0f};

#pragma unroll
    for (int h4 = 0; h4 < 16; ++h4) {
        float4 w4[4];
#pragma unroll
        for (int gq = 0; gq < 4; ++gq) w4[gq] = w2s[h4][gq * 16 + gp];
#pragma unroll
        for (int pp = 0; pp < 2; ++pp) {
#pragma unroll
            for (int kk = 0; kk < 4; ++kk) {
                const float4 hv =
                    *(const float4*)&h1s[wave][pp * 16 + kq * 4 + kk][h4 * 4];
#pragma unroll
                for (int gq = 0; gq < 4; ++gq) {
                    acc[pp][kk][gq] = __builtin_elementwise_fma(
                        (v2f){hv.x, hv.y}, (v2f){w4[gq].x, w4[gq].y},
                        acc[pp][kk][gq]);
                    acc[pp][kk][gq] = __builtin_elementwise_fma(
                        (v2f){hv.z, hv.w}, (v2f){w4[gq].z, w4[gq].w},
                        acc[pp][kk][gq]);
                }
            }
        }
    }

#pragma unroll
    for (int pp = 0; pp < 2; ++pp) {
        float s[4];
#pragma unroll
        for (int gq = 0; gq < 4; ++gq) {
            s[gq] = 0.0f;
#pragma unroll
            for (int kk = 0; kk < 4; ++kk) {
                const float v = acc[pp][kk][gq].x + acc[pp][kk][gq].y;
                s[gq] += fmaxf(v, 0.0f);
            }
        }
#pragma unroll
        for (int off = 16; off <= 32; off <<= 1)
#pragma unroll
            for (int gq = 0; gq < 4; ++gq)
                s[gq] += __shfl_xor(s[gq], off, 64);

        out[(p0 + pp) * H_DIM + kq * 16 + gp] = s[kq] * (1.0f / 16.0f);
    }
}

extern "C" void kernel_launch(void* const* d_in, const int* in_sizes, int n_in,
                              void* d_out, int out_size, void* d_ws, size_t ws_size,
                              hipStream_t stream) {
    (void)in_sizes; (void)n_in; (void)out_size; (void)ws_size;
    const float* x  = (const float*)d_in[0];
    const float* W1 = (const float*)d_in[1];
    const float* b1 = (const float*)d_in[2];
    const float* W2 = (const float*)d_in[3];
    const float* b2 = (const float*)d_in[4];
    float* out = (float*)d_out;

    // workspace: [0,1M) bfrag, [1M,3M) vals (u32), [3M,4M) idxs (u16)
    u16*      bfrag = (u16*)d_ws;
    unsigned* vals  = (unsigned*)((char*)d_ws + (1u << 20));
    u16*      idxs  = (u16*)((char*)d_ws + (3u << 20));

    const float4* x4 = (const float4*)x;

    prep_kernel<<<N_PTS / 256, 256, 0, stream>>>(x4, bfrag);
    knn_kernel <<<N_PTS / 16 * 2, 256, 0, stream>>>(x4, bfrag, vals, idxs);
    mlp_kernel <<<N_PTS / 8,   256, 0, stream>>>(
        x4, vals, idxs, (const float4*)W2, W1, b1, b2, out);
}

// Round 11
// 219.655 us; speedup vs baseline: 1.0016x; 1.0016x over previous
//
#include <hip/hip_runtime.h>
#include <math.h>

#define N_PTS 16384
#define K_NBR 16
#define H_DIM 64
#define CAP   38              // per-query/per-part buffer; 4*16*CAP*8+64 = 19520
#define NBLK  (N_PTS / 16)    // 1024 column-blocks of 16 candidates
#define HBLK  (NBLK / 2)      // 512 col-blocks per half
#define PBLK  (HBLK / 4)      // 128 col-blocks per wave-part

typedef unsigned long long u64;
typedef unsigned short u16;
typedef float v2f   __attribute__((ext_vector_type(2)));
typedef float f32x4 __attribute__((ext_vector_type(4)));
typedef short bf16x8 __attribute__((ext_vector_type(8)));

// key = (order-preserving float bits, ~idx): sorts by value desc then idx asc
__device__ __forceinline__ u64 mkkey(unsigned vbits, unsigned idx) {
    unsigned of = vbits ^ (unsigned)(((int)vbits >> 31) | 0x80000000);
    return ((u64)of << 32) | (unsigned)(~idx);
}
__device__ __forceinline__ unsigned keyidx(u64 k) { return ~(unsigned)k; }

__device__ __forceinline__ float readlane_f(float v, int l) {
    return __uint_as_float(__builtin_amdgcn_readlane(__float_as_uint(v), l));
}

// order-preserving float<->uint (tau stored in LDS as monotone uint)
__device__ __forceinline__ unsigned ofsbits(float f) {
    unsigned b = __float_as_uint(f);
    return b ^ ((unsigned)((int)b >> 31) | 0x80000000u);
}
__device__ __forceinline__ float inv_ofs(unsigned u) {
    return __uint_as_float(u ^ (~(unsigned)((int)u >> 31) | 0x80000000u));
}

// bf16 RNE helpers (identical arithmetic in prep and knn query-side)
__device__ __forceinline__ u16 f2bf(float f) {
    unsigned u = __float_as_uint(f);
    return (u16)((u + 0x7FFFu + ((u >> 16) & 1u)) >> 16);
}
__device__ __forceinline__ float bf2f(u16 b) {
    return __uint_as_float(((unsigned)b) << 16);
}

// 64-lane bitonic ascending sort, float
__device__ __forceinline__ float wave_sort_f32(float v, int lane) {
#pragma unroll
    for (int k = 2; k <= 64; k <<= 1) {
#pragma unroll
        for (int j = k >> 1; j > 0; j >>= 1) {
            float o = __shfl_xor(v, j, 64);
            bool keep_min = (((lane & k) == 0) == ((lane & j) == 0));
            v = keep_min ? fminf(v, o) : fmaxf(v, o);
        }
    }
    return v;
}
// 64-lane bitonic ascending sort, u64 keys
__device__ __forceinline__ u64 wave_sort_u64(u64 v, int lane) {
#pragma unroll
    for (int k = 2; k <= 64; k <<= 1) {
#pragma unroll
        for (int j = k >> 1; j > 0; j >>= 1) {
            u64 o = __shfl_xor((unsigned long long)v, j, 64);
            bool keep_min = (((lane & k) == 0) == ((lane & j) == 0));
            u64 mn = (v < o) ? v : o;
            u64 mx = (v < o) ? o : v;
            v = keep_min ? mn : mx;
        }
    }
    return v;
}
// two independent 32-lane ascending sorts (halves of the wave); all shfl
// distances <= 16 so lanes never cross the 32-boundary.
__device__ __forceinline__ u64 half32_sort_u64(u64 v, int lane) {
    const int l = lane & 31;
#pragma unroll
    for (int k = 2; k <= 32; k <<= 1) {
#pragma unroll
        for (int j = k >> 1; j > 0; j >>= 1) {
            u64 o = __shfl_xor((unsigned long long)v, j, 64);
            bool keep_min = (((l & k) == 0) == ((l & j) == 0));
            u64 mn = (v < o) ? v : o;
            u64 mx = (v < o) ? o : v;
            v = keep_min ? mn : mx;
        }
    }
    return v;
}

// raise tau to 16th-largest of per-lane max VALUES, drop entries below.
// Exact invariant: tau <= 16th-largest value in buffer (>= 16 entries >= tau
// retained; boundary ties kept).
struct CompRes { int nc; float tau; };
__device__ __attribute__((noinline)) CompRes wave_compact(uint2* buf, int cnt,
                                                          int lane) {
    float lm = -INFINITY;
    for (int s = lane; s < cnt; s += 64)
        lm = fmaxf(lm, __uint_as_float(buf[s].x));
    const float tv = readlane_f(wave_sort_f32(lm, lane), 48);
    int nc = 0;
    for (int s0 = 0; s0 < cnt; s0 += 64) {
        const int s = s0 + lane;
        uint2 e = make_uint2(0u, 0u);
        bool keep = false;
        if (s < cnt) { e = buf[s]; keep = (__uint_as_float(e.x) >= tv); }
        const u64 km = __ballot(keep);
        if (keep) {
            int pfx = (int)__popcll(km & ((1ull << lane) - 1));
            buf[nc + pfx] = e;   // write idx <= read idx: safe
        }
        nc += (int)__popcll(km);
    }
    CompRes r; r.nc = nc; r.tau = tv;
    return r;
}

// ---------------- prep: fragment array for bf16x3-split MFMA ---------------
// Score(i,j) = 2*xi.xj - ||xj||^2  (row term -||xi||^2 is rank-invariant).
// K-slot map (k = c + 4p, c=0..3): pairs p:(sa,sb) = (0,0)(0,1)(1,0)(0,2)
// (2,0)(1,1)  [hh,hm,mh,hl,lh,mm of split3]; k=24..26: query-side 1.0,
// cand-side split3(-xx); k=27..31: 0.  Dropped terms (ml,lm,ll) ~2^-27 rel.
__global__ __launch_bounds__(256) void prep_kernel(const float4* __restrict__ x4,
                                                   u16* __restrict__ bf) {
    const int i = blockIdx.x * 256 + threadIdx.x;
    const float4 v = x4[i];
    float xx;
    {
#pragma clang fp contract(off)
        float s0 = v.x * v.x, s1 = v.y * v.y, s2 = v.z * v.z, s3 = v.w * v.w;
        xx = ((s0 + s1) + s2) + s3;
    }
    float c[4] = {v.x, v.y, v.z, v.w};
    u16 H[4], M[4], L[4];
#pragma unroll
    for (int q = 0; q < 4; ++q) {
        float f = c[q];
        u16 h = f2bf(f);            float fh = bf2f(h);
        u16 m = f2bf(f - fh);       float fm = bf2f(m);
        u16 l = f2bf(f - fh - fm);
        H[q] = h; M[q] = m; L[q] = l;
    }
    const float nx = -xx;
    u16 X0 = f2bf(nx);              float x0f = bf2f(X0);
    u16 X1 = f2bf(nx - x0f);        float x1f = bf2f(X1);
    u16 X2 = f2bf(nx - x0f - x1f);
    u16 o[32];
#pragma unroll
    for (int q = 0; q < 4; ++q) {
        o[q]      = H[q];  // p0: sb=hi
        o[4 + q]  = M[q];  // p1: sb=mid
        o[8 + q]  = H[q];  // p2: sb=hi
        o[12 + q] = L[q];  // p3: sb=lo
        o[16 + q] = H[q];  // p4: sb=hi
        o[20 + q] = M[q];  // p5: sb=mid
    }
    o[24] = X0; o[25] = X1; o[26] = X2;
    o[27] = 0; o[28] = 0; o[29] = 0; o[30] = 0; o[31] = 0;
    uint4* dst = (uint4*)(bf + (size_t)i * 32);
#pragma unroll
    for (int q2 = 0; q2 < 4; ++q2) {
        uint4 w;
        w.x = (unsigned)o[q2 * 8 + 0] | ((unsigned)o[q2 * 8 + 1] << 16);
        w.y = (unsigned)o[q2 * 8 + 2] | ((unsigned)o[q2 * 8 + 3] << 16);
        w.z = (unsigned)o[q2 * 8 + 4] | ((unsigned)o[q2 * 8 + 5] << 16);
        w.w = (unsigned)o[q2 * 8 + 6] | ((unsigned)o[q2 * 8 + 7] << 16);
        dst[q2] = w;
    }
}

// ---------------- kNN: two-phase, half-column grid, LDS-limited occupancy --
// R10 post-mortem: the half-column grid raised occupancy (34->49%) but
// __launch_bounds__(256,6) squeezed the allocator below the ~52-VGPR
// working set -> VGPR 40 + 48 MB scratch spill (third spill in three
// attempts at register pressure). Rule learned: NEVER bound below the
// proven (256,4) codegen. This version: (256,4) (R7-proven 52 VGPR, no
// spill) + CAP 38 -> LDS 19520 B -> 8 blocks/CU by LDS alone. Grid 2048
// = exactly 8/CU, no tail; 32 waves/CU = 8 waves/SIMD (register-feasible
// at 52 VGPR). Algorithm identical to R10 (exact half top-16 per query;
// mlp merges 32->16).
__global__ __launch_bounds__(256, 4) void knn_kernel(
        const float4* __restrict__ x4,
        const u16* __restrict__ bfrag,
        unsigned* __restrict__ vals,
        u16* __restrict__ idxs) {
    __shared__ __align__(16) uint2 buf[4][16][CAP];   // 19456 B
    __shared__ unsigned tau_sh[16];                   // +64 B = 19520 B
    const int lane = threadIdx.x & 63;
    const int wave = threadIdx.x >> 6;
    const int q    = lane & 15;
    const int g    = lane >> 4;
    const int qgrp = blockIdx.x >> 1;
    const int half = blockIdx.x & 1;
    const int rowbase = qgrp * 16;
    const int pblk = half * HBLK + wave * PBLK;   // part's first 16-col block

    // ---- query fragment (B operand): query = q, k-chunk = g ----
    const float4 xi = x4[rowbase + q];
    u16 Ha[4], Ma[4], La[4];
    {
        float yy[4] = {2.f * xi.x, 2.f * xi.y, 2.f * xi.z, 2.f * xi.w};
#pragma unroll
        for (int c = 0; c < 4; ++c) {
            u16 h = f2bf(yy[c]);             float fh = bf2f(h);
            u16 m = f2bf(yy[c] - fh);        float fm = bf2f(m);
            u16 l = f2bf(yy[c] - fh - fm);
            Ha[c] = h; Ma[c] = m; La[c] = l;
        }
    }
    bf16x8 qfrag;
    {
        const u16 ONEB = 0x3F80;  // bf16 1.0
#pragma unroll
        for (int c = 0; c < 4; ++c) {
            u16 lo, hi;
            if (g == 0)      { lo = Ha[c]; hi = Ha[c]; }  // p0:hi  p1:hi
            else if (g == 1) { lo = Ma[c]; hi = Ha[c]; }  // p2:mid p3:hi
            else if (g == 2) { lo = La[c]; hi = Ma[c]; }  // p4:lo  p5:mid
            else             { lo = (c < 3) ? ONEB : 0; hi = 0; }  // k24..26=1
            qfrag[c]     = (short)lo;
            qfrag[c + 4] = (short)hi;
        }
    }
    const f32x4 zacc = {0.f, 0.f, 0.f, 0.f};
    // candidate fragment (A operand): cand-in-block = lane&15, k-chunk = g
    const bf16x8* bp = (const bf16x8*)bfrag + (size_t)pblk * 64 + (q * 4 + g);

    // ================= Phase A: sampled class-maxima (stride-2 blocks) =====
    f32x4 mx = {-INFINITY, -INFINITY, -INFINITY, -INFINITY};
    {
        bf16x8 A0[4], A1[4];
#pragma unroll
        for (int i = 0; i < 4; ++i) A0[i] = bp[(2 * i) * 64];        // 0,2,4,6
#pragma unroll
        for (int i = 0; i < 4; ++i) A1[i] = bp[(8 + 2 * i) * 64];    // 8..14
        const bf16x8* pa = bp + 16 * 64;

#define PROCA(BUF) do {                                                      \
    _Pragma("unroll")                                                        \
    for (int i = 0; i < 4; ++i) {                                            \
        const f32x4 aa = __builtin_amdgcn_mfma_f32_16x16x32_bf16(            \
            BUF[i], qfrag, zacc, 0, 0, 0);                                   \
        mx[0] = fmaxf(mx[0], aa[0]); mx[1] = fmaxf(mx[1], aa[1]);            \
        mx[2] = fmaxf(mx[2], aa[2]); mx[3] = fmaxf(mx[3], aa[3]);            \
    }                                                                        \
} while (0)

        for (int it = 0; it < 7; ++it) {   // 64 sampled blocks of the half
            PROCA(A0);
#pragma unroll
            for (int i = 0; i < 4; ++i) A0[i] = pa[(2 * i) * 64];
            PROCA(A1);
#pragma unroll
            for (int i = 0; i < 4; ++i) A1[i] = pa[(8 + 2 * i) * 64];
            pa += 16 * 64;
        }
        PROCA(A0);
        PROCA(A1);
#undef PROCA
    }

    // ---- combine: 64 class-maxima per query -> tau = 16th largest ----
    // (4 waves x 4 g x 4 reg disjoint classes within this half)
    {
        float* am = (float*)&buf[0][0][0];          // 4 KB scratch alias
        const int base = wave * 256 + q * 16 + g * 4;
        am[base + 0] = mx[0]; am[base + 1] = mx[1];
        am[base + 2] = mx[2]; am[base + 3] = mx[3];
        __syncthreads();
#pragma unroll
        for (int rr = 0; rr < 4; ++rr) {
            const int r = wave * 4 + rr;
            float v = am[(lane >> 4) * 256 + r * 16 + (lane & 15)];
            v = wave_sort_f32(v, lane);
            if (lane == 48) tau_sh[r] = ofsbits(v);  // 16th largest of 64
        }
        __syncthreads();
    }
    float tau = inv_ofs(tau_sh[q]);        // half-tight, fixed for Phase B

    unsigned cq = 0;                        // per-query count (lane-wise,
    uint2* bq = &buf[wave][q][0];           //  replicated across the 4 g-lanes)
    const unsigned gid4 = (unsigned)(g * 4);

// lean lane-wise insert; cold path compacts the overflowing queries
// (ballot/ctz-driven), raising their LOCAL taus.
#define INSERT4(AV, CB) do {                                                 \
    for (;;) {                                                               \
        const bool k0 = (AV)[0] >= tau, k1 = (AV)[1] >= tau;                 \
        const bool k2 = (AV)[2] >= tau, k3 = (AV)[3] >= tau;                 \
        const int cnt = (int)k0 + (int)k1 + (int)k2 + (int)k3;               \
        const int sa = __shfl_xor(cnt, 16, 64);                              \
        const int sb = __shfl_xor(cnt, 32, 64);                              \
        const int sc = __shfl_xor(sa, 32, 64);                               \
        const int tot = cnt + sa + sb + sc;                                  \
        const int pf  = ((g & 1) ? sa : 0) + ((g & 2) ? (sb + sc) : 0);      \
        const u64 ovm = __ballot(cq + (unsigned)tot > CAP);                  \
        if (__builtin_expect(ovm == 0, 1)) {                                 \
            unsigned slot = cq + (unsigned)pf;                               \
            if (k0) bq[slot++] = make_uint2(__float_as_uint((AV)[0]), (CB)); \
            if (k1) bq[slot++] = make_uint2(__float_as_uint((AV)[1]), (CB)+1);\
            if (k2) bq[slot++] = make_uint2(__float_as_uint((AV)[2]), (CB)+2);\
            if (k3) bq[slot++] = make_uint2(__float_as_uint((AV)[3]), (CB)+3);\
            cq += (unsigned)tot;                                             \
            break;                                                           \
        }                                                                    \
        u64 ov = ovm & 0xFFFFull;                                            \
        while (ov) {                                                         \
            const int r = (int)__builtin_ctzll(ov); ov &= ov - 1;            \
            const unsigned cr =                                              \
                (unsigned)__builtin_amdgcn_readlane((int)cq, r);             \
            CompRes res = wave_compact(&buf[wave][r][0], (int)cr, lane);     \
            if (q == r) { cq = (unsigned)res.nc;                             \
                          tau = fmaxf(tau, res.tau); }                       \
        }                                                                    \
    }                                                                        \
} while (0)

// one 16x16 block: MFMA -> 3-fmax gate -> rare insert
#define PROC4(BUF, TB) do {                                                  \
    f32x4 A4_[4];                                                            \
    _Pragma("unroll")                                                        \
    for (int i = 0; i < 4; ++i)                                              \
        A4_[i] = __builtin_amdgcn_mfma_f32_16x16x32_bf16(BUF[i], qfrag,      \
                                                         zacc, 0, 0, 0);     \
    _Pragma("unroll")                                                        \
    for (int i = 0; i < 4; ++i) {                                            \
        const f32x4 av = A4_[i];                                             \
        const float m4 = fmaxf(fmaxf(av[0], av[1]), fmaxf(av[2], av[3]));    \
        if (__ballot(m4 >= tau))                                             \
            INSERT4(av, (unsigned)(((TB) + i) * 16) + gid4);                 \
    }                                                                        \
} while (0)

    // ================= Phase B: full stream, fixed tau, 2-deep =============
    {
        bf16x8 B0[4], B1[4];
#pragma unroll
        for (int i = 0; i < 4; ++i) B0[i] = bp[i * 64];
#pragma unroll
        for (int i = 0; i < 4; ++i) B1[i] = bp[(4 + i) * 64];
        const bf16x8* pA = bp + 8 * 64;    // refill source for B0 (block t+8)
        const bf16x8* pB = bp + 12 * 64;   // refill source for B1 (block t+12)

        int t = 0;
        for (; t < PBLK - 8; t += 8) {
            PROC4(B0, pblk + t);
#pragma unroll
            for (int i = 0; i < 4; ++i) B0[i] = pA[i * 64];
            pA += 8 * 64;
            PROC4(B1, pblk + t + 4);
#pragma unroll
            for (int i = 0; i < 4; ++i) B1[i] = pB[i * 64];
            pB += 8 * 64;
        }
        PROC4(B0, pblk + t);               // blocks 120..123
        PROC4(B1, pblk + t + 4);           // blocks 124..127
    }
#undef PROC4
#undef INSERT4

    // ---- per-part finalize: park top-16 keys (c <= CAP=38 < 64 always) ----
#pragma unroll 1
    for (int r = 0; r < 16; ++r) {
        int c = __builtin_amdgcn_readlane((int)cq, r);
        uint2* br = &buf[wave][r][0];
        if (c <= 16) {                     // typical: park (merge re-sorts)
            if (lane < 16) {
                u64 key = 0;
                if (lane < c) { const uint2 e = br[lane]; key = mkkey(e.x, e.y); }
                *(u64*)&buf[wave][r][lane] = key;
            }
        } else {
            u64 key = 0;                   // sentinel < any real key
            if (lane < c) { const uint2 e = br[lane]; key = mkkey(e.x, e.y); }
            key = wave_sort_u64(key, lane);
            if (lane >= 48)
                *(u64*)&buf[wave][r][lane - 48] = key;  // top-16, slots 0..15
        }
    }

    // ---- in-block merge: 64 keys/query (4 parts x 16) -> half top-16 ----
    __syncthreads();
#pragma unroll
    for (int rr = 0; rr < 4; ++rr) {
        const int r2 = wave * 4 + rr;
        u64 key = *(const u64*)&buf[lane >> 4][r2][lane & 15];
        key = wave_sort_u64(key, lane);
        if (lane >= 48) {
            const int o = (rowbase + r2) * 32 + half * 16 + (lane - 48);
            vals[o] = (unsigned)(key >> 32);       // ofs-transformed value
            idxs[o] = (u16)keyidx(key);            // idx < 16384 fits u16
        }
    }
}

// ---------------- edge-feature MLP: 32->16 merge + gather + hoisted W2 -----
__global__ __launch_bounds__(256, 2) void mlp_kernel(
        const float4* __restrict__ x4,
        const unsigned* __restrict__ vals,
        const u16* __restrict__ idxs,
        const float4* __restrict__ W2f4,
        const float* __restrict__ W1,
        const float* __restrict__ b1,
        const float* __restrict__ b2,
        float* __restrict__ out) {
    __shared__ __align__(16) float4 w2s[16][64];     // 16 KB, h4-major
    __shared__ __align__(16) float  h1s[4][32][68];  // 34 KB, per-wave
    __shared__ __align__(16) float4 xjs[4][32];      // 2 KB, per-wave gather
    const int lane = threadIdx.x & 63;
    const int wave = threadIdx.x >> 6;
    const int kq   = lane >> 4;
    const int gp   = lane & 15;
    const int p0   = (blockIdx.x * 4 + wave) * 2;    // 2 points per wave

    for (int q = threadIdx.x; q < 1024; q += 256)
        w2s[q & 15][q >> 4] = W2f4[q];               // w2s[h4][g]
    __syncthreads();

    float w1r[8];
#pragma unroll
    for (int c = 0; c < 8; ++c) w1r[c] = W1[lane * 8 + c];
    const float b1r = b1[lane];
    float b2r[4];
#pragma unroll
    for (int gq = 0; gq < 4; ++gq) b2r[gq] = b2[gq * 16 + gp];

    // merge the two half-top-16s (exact: same value bits + idx tie-break as
    // the knn-side keys), then gather winners. Each 32-lane group handles
    // one point's 32 candidates; both halves have >=16 real keys so the
    // top-16 are always real.
    {
        const int pp = lane >> 5;                    // 0 or 1
        const int j  = lane & 31;
        const int o  = (p0 + pp) * 32 + j;
        u64 key = ((u64)vals[o] << 32) | (unsigned)(~(unsigned)idxs[o]);
        key = half32_sort_u64(key, lane);
        if ((lane & 31) >= 16) {
            const int nb = (int)((~(unsigned)key) & 0xFFFFu);
            xjs[wave][pp * 16 + ((lane & 31) - 16)] = x4[nb];
        }
    }
    // wave-private LDS + in-wave vmcnt/lgkmcnt ordering: no barrier

    // layer 1 for both points (lane = hidden feature h)
#pragma unroll
    for (int pp = 0; pp < 2; ++pp) {
        const float4 xi = x4[p0 + pp];
        float hb = b1r;
        hb = fmaf(w1r[4] - w1r[0], xi.x, hb);
        hb = fmaf(w1r[5] - w1r[1], xi.y, hb);
        hb = fmaf(w1r[6] - w1r[2], xi.z, hb);
        hb = fmaf(w1r[7] - w1r[3], xi.w, hb);
#pragma unroll
        for (int k = 0; k < K_NBR; ++k) {
            const float4 xj = xjs[wave][pp * 16 + k];
            float h = hb;
            h = fmaf(w1r[0], xj.x, h);
            h = fmaf(w1r[1], xj.y, h);
            h = fmaf(w1r[2], xj.z, h);
            h = fmaf(w1r[3], xj.w, h);
            h1s[wave][pp * 16 + k][lane] = fmaxf(h, 0.0f);
        }
    }

    // layer 2: acc[pp][kk][gq] (packed pairs over h), h4-outer, w4 hoisted
    v2f acc[2][4][4];
#pragma unroll
    for (int pp = 0; pp < 2; ++pp)
#pragma unroll
        for (int kk = 0; kk < 4; ++kk)
#pragma unroll
            for (int gq = 0; gq < 4; ++gq)
                acc[pp][kk][gq] = (v2f){b2r[gq], 0.0f};

#pragma unroll
    for (int h4 = 0; h4 < 16; ++h4) {
        float4 w4[4];
#pragma unroll
        for (int gq = 0; gq < 4; ++gq) w4[gq] = w2s[h4][gq * 16 + gp];
#pragma unroll
        for (int pp = 0; pp < 2; ++pp) {
#pragma unroll
            for (int kk = 0; kk < 4; ++kk) {
                const float4 hv =
                    *(const float4*)&h1s[wave][pp * 16 + kq * 4 + kk][h4 * 4];
#pragma unroll
                for (int gq = 0; gq < 4; ++gq) {
                    acc[pp][kk][gq] = __builtin_elementwise_fma(
                        (v2f){hv.x, hv.y}, (v2f){w4[gq].x, w4[gq].y},
                        acc[pp][kk][gq]);
                    acc[pp][kk][gq] = __builtin_elementwise_fma(
                        (v2f){hv.z, hv.w}, (v2f){w4[gq].z, w4[gq].w},
                        acc[pp][kk][gq]);
                }
            }
        }
    }

#pragma unroll
    for (int pp = 0; pp < 2; ++pp) {
        float s[4];
#pragma unroll
        for (int gq = 0; gq < 4; ++gq) {
            s[gq] = 0.0f;
#pragma unroll
            for (int kk = 0; kk < 4; ++kk) {
                const float v = acc[pp][kk][gq].x + acc[pp][kk][gq].y;
                s[gq] += fmaxf(v, 0.0f);
            }
        }
#pragma unroll
        for (int off = 16; off <= 32; off <<= 1)
#pragma unroll
            for (int gq = 0; gq < 4; ++gq)
                s[gq] += __shfl_xor(s[gq], off, 64);

        out[(p0 + pp) * H_DIM + kq * 16 + gp] = s[kq] * (1.0f / 16.0f);
    }
}

extern "C" void kernel_launch(void* const* d_in, const int* in_sizes, int n_in,
                              void* d_out, int out_size, void* d_ws, size_t ws_size,
                              hipStream_t stream) {
    (void)in_sizes; (void)n_in; (void)out_size; (void)ws_size;
    const float* x  = (const float*)d_in[0];
    const float* W1 = (const float*)d_in[1];
    const float* b1 = (const float*)d_in[2];
    const float* W2 = (const float*)d_in[3];
    const float* b2 = (const float*)d_in[4];
    float* out = (float*)d_out;

    // workspace: [0,1M) bfrag, [1M,3M) vals (u32), [3M,4M) idxs (u16)
    u16*      bfrag = (u16*)d_ws;
    unsigned* vals  = (unsigned*)((char*)d_ws + (1u << 20));
    u16*      idxs  = (u16*)((char*)d_ws + (3u << 20));

    const float4* x4 = (const float4*)x;

    prep_kernel<<<N_PTS / 256, 256, 0, stream>>>(x4, bfrag);
    knn_kernel <<<N_PTS / 16 * 2, 256, 0, stream>>>(x4, bfrag, vals, idxs);
    mlp_kernel <<<N_PTS / 8,   256, 0, stream>>>(
        x4, vals, idxs, (const float4*)W2, W1, b1, b2, out);
}

// Round 12
// 215.449 us; speedup vs baseline: 1.0211x; 1.0195x over previous
//
#include <hip/hip_runtime.h>
#include <math.h>

#define N_PTS 16384
#define K_NBR 16
#define H_DIM 64
#define CAP   38              // per-query/per-part buffer; 4*16*CAP*8+64 = 19520
#define NBLK  (N_PTS / 16)    // 1024 column-blocks of 16 candidates
#define HBLK  (NBLK / 2)      // 512 col-blocks per half
#define PBLK  (HBLK / 4)      // 128 col-blocks per wave-part

typedef unsigned long long u64;
typedef unsigned short u16;
typedef float v2f   __attribute__((ext_vector_type(2)));
typedef float f32x4 __attribute__((ext_vector_type(4)));
typedef short bf16x8 __attribute__((ext_vector_type(8)));

// key = (order-preserving float bits, ~idx): sorts by value desc then idx asc
__device__ __forceinline__ u64 mkkey(unsigned vbits, unsigned idx) {
    unsigned of = vbits ^ (unsigned)(((int)vbits >> 31) | 0x80000000);
    return ((u64)of << 32) | (unsigned)(~idx);
}
__device__ __forceinline__ unsigned keyidx(u64 k) { return ~(unsigned)k; }

__device__ __forceinline__ float readlane_f(float v, int l) {
    return __uint_as_float(__builtin_amdgcn_readlane(__float_as_uint(v), l));
}

// order-preserving float<->uint (tau stored in LDS as monotone uint)
__device__ __forceinline__ unsigned ofsbits(float f) {
    unsigned b = __float_as_uint(f);
    return b ^ ((unsigned)((int)b >> 31) | 0x80000000u);
}
__device__ __forceinline__ float inv_ofs(unsigned u) {
    return __uint_as_float(u ^ (~(unsigned)((int)u >> 31) | 0x80000000u));
}

// bf16 RNE helpers (identical arithmetic in prep and knn query-side)
__device__ __forceinline__ u16 f2bf(float f) {
    unsigned u = __float_as_uint(f);
    return (u16)((u + 0x7FFFu + ((u >> 16) & 1u)) >> 16);
}
__device__ __forceinline__ float bf2f(u16 b) {
    return __uint_as_float(((unsigned)b) << 16);
}

// 64-lane bitonic ascending sort, float
__device__ __forceinline__ float wave_sort_f32(float v, int lane) {
#pragma unroll
    for (int k = 2; k <= 64; k <<= 1) {
#pragma unroll
        for (int j = k >> 1; j > 0; j >>= 1) {
            float o = __shfl_xor(v, j, 64);
            bool keep_min = (((lane & k) == 0) == ((lane & j) == 0));
            v = keep_min ? fminf(v, o) : fmaxf(v, o);
        }
    }
    return v;
}
// 64-lane bitonic ascending sort, u64 keys
__device__ __forceinline__ u64 wave_sort_u64(u64 v, int lane) {
#pragma unroll
    for (int k = 2; k <= 64; k <<= 1) {
#pragma unroll
        for (int j = k >> 1; j > 0; j >>= 1) {
            u64 o = __shfl_xor((unsigned long long)v, j, 64);
            bool keep_min = (((lane & k) == 0) == ((lane & j) == 0));
            u64 mn = (v < o) ? v : o;
            u64 mx = (v < o) ? o : v;
            v = keep_min ? mn : mx;
        }
    }
    return v;
}
// two independent 32-lane ascending sorts (halves of the wave); all shfl
// distances <= 16 so lanes never cross the 32-boundary.
__device__ __forceinline__ u64 half32_sort_u64(u64 v, int lane) {
    const int l = lane & 31;
#pragma unroll
    for (int k = 2; k <= 32; k <<= 1) {
#pragma unroll
        for (int j = k >> 1; j > 0; j >>= 1) {
            u64 o = __shfl_xor((unsigned long long)v, j, 64);
            bool keep_min = (((l & k) == 0) == ((l & j) == 0));
            u64 mn = (v < o) ? v : o;
            u64 mx = (v < o) ? o : v;
            v = keep_min ? mn : mx;
        }
    }
    return v;
}

// raise tau to 16th-largest of per-lane max VALUES, drop entries below.
// Exact invariant: tau <= 16th-largest value in buffer (>= 16 entries >= tau
// retained; boundary ties kept).
struct CompRes { int nc; float tau; };
__device__ __attribute__((noinline)) CompRes wave_compact(uint2* buf, int cnt,
                                                          int lane) {
    float lm = -INFINITY;
    for (int s = lane; s < cnt; s += 64)
        lm = fmaxf(lm, __uint_as_float(buf[s].x));
    const float tv = readlane_f(wave_sort_f32(lm, lane), 48);
    int nc = 0;
    for (int s0 = 0; s0 < cnt; s0 += 64) {
        const int s = s0 + lane;
        uint2 e = make_uint2(0u, 0u);
        bool keep = false;
        if (s < cnt) { e = buf[s]; keep = (__uint_as_float(e.x) >= tv); }
        const u64 km = __ballot(keep);
        if (keep) {
            int pfx = (int)__popcll(km & ((1ull << lane) - 1));
            buf[nc + pfx] = e;   // write idx <= read idx: safe
        }
        nc += (int)__popcll(km);
    }
    CompRes r; r.nc = nc; r.tau = tv;
    return r;
}

// ---------------- prep: fragment array for bf16x3-split MFMA ---------------
// Score(i,j) = 2*xi.xj - ||xj||^2  (row term -||xi||^2 is rank-invariant).
// K-slot map (k = c + 4p, c=0..3): pairs p:(sa,sb) = (0,0)(0,1)(1,0)(0,2)
// (2,0)(1,1)  [hh,hm,mh,hl,lh,mm of split3]; k=24..26: query-side 1.0,
// cand-side split3(-xx); k=27..31: 0.  Dropped terms (ml,lm,ll) ~2^-27 rel.
__global__ __launch_bounds__(256) void prep_kernel(const float4* __restrict__ x4,
                                                   u16* __restrict__ bf) {
    const int i = blockIdx.x * 256 + threadIdx.x;
    const float4 v = x4[i];
    float xx;
    {
#pragma clang fp contract(off)
        float s0 = v.x * v.x, s1 = v.y * v.y, s2 = v.z * v.z, s3 = v.w * v.w;
        xx = ((s0 + s1) + s2) + s3;
    }
    float c[4] = {v.x, v.y, v.z, v.w};
    u16 H[4], M[4], L[4];
#pragma unroll
    for (int q = 0; q < 4; ++q) {
        float f = c[q];
        u16 h = f2bf(f);            float fh = bf2f(h);
        u16 m = f2bf(f - fh);       float fm = bf2f(m);
        u16 l = f2bf(f - fh - fm);
        H[q] = h; M[q] = m; L[q] = l;
    }
    const float nx = -xx;
    u16 X0 = f2bf(nx);              float x0f = bf2f(X0);
    u16 X1 = f2bf(nx - x0f);        float x1f = bf2f(X1);
    u16 X2 = f2bf(nx - x0f - x1f);
    u16 o[32];
#pragma unroll
    for (int q = 0; q < 4; ++q) {
        o[q]      = H[q];  // p0: sb=hi
        o[4 + q]  = M[q];  // p1: sb=mid
        o[8 + q]  = H[q];  // p2: sb=hi
        o[12 + q] = L[q];  // p3: sb=lo
        o[16 + q] = H[q];  // p4: sb=hi
        o[20 + q] = M[q];  // p5: sb=mid
    }
    o[24] = X0; o[25] = X1; o[26] = X2;
    o[27] = 0; o[28] = 0; o[29] = 0; o[30] = 0; o[31] = 0;
    uint4* dst = (uint4*)(bf + (size_t)i * 32);
#pragma unroll
    for (int q2 = 0; q2 < 4; ++q2) {
        uint4 w;
        w.x = (unsigned)o[q2 * 8 + 0] | ((unsigned)o[q2 * 8 + 1] << 16);
        w.y = (unsigned)o[q2 * 8 + 2] | ((unsigned)o[q2 * 8 + 3] << 16);
        w.z = (unsigned)o[q2 * 8 + 4] | ((unsigned)o[q2 * 8 + 5] << 16);
        w.w = (unsigned)o[q2 * 8 + 6] | ((unsigned)o[q2 * 8 + 7] << 16);
        dst[q2] = w;
    }
}

// ---------------- kNN: two-phase, 8-waves/SIMD via MINIMAL register set ----
// R11 post-mortem: occupancy stuck at 4 waves/SIMD because total regs =
// ~52 arch VGPR + ~32-48 AGPR (MFMA acc; VGPR_Count hides AGPRs on the
// unified gfx950 file) lands in the 65-128 tier. The dual prefetch
// buffers (32 VGPR) are the budget-breaker -- and at 8 waves/SIMD TLP
// covers L2 latency without them. This version: SINGLE B[4] buffer
// (16 VGPR), per-unit {4 loads -> 4 MFMA -> gate}; total regs ~56 <= 64
// tier -> 8 waves/SIMD legal. __launch_bounds__(256,8) + 2048-block
// half-column grid + 19520 B LDS -> whole grid resident (8 blk/CU).
// R8/R10 spilled because their TRUE working set exceeded the budget;
// this one fits. Algorithm identical to R11 (exact half top-16/query).
__global__ __launch_bounds__(256, 8) void knn_kernel(
        const float4* __restrict__ x4,
        const u16* __restrict__ bfrag,
        unsigned* __restrict__ vals,
        u16* __restrict__ idxs) {
    __shared__ __align__(16) uint2 buf[4][16][CAP];   // 19456 B
    __shared__ unsigned tau_sh[16];                   // +64 B = 19520 B
    const int lane = threadIdx.x & 63;
    const int wave = threadIdx.x >> 6;
    const int q    = lane & 15;
    const int g    = lane >> 4;
    const int qgrp = blockIdx.x >> 1;
    const int half = blockIdx.x & 1;
    const int rowbase = qgrp * 16;
    const int pblk = half * HBLK + wave * PBLK;   // part's first 16-col block

    // ---- query fragment (B operand): query = q, k-chunk = g ----
    bf16x8 qfrag;
    {
        const float4 xi = x4[rowbase + q];
        u16 Ha[4], Ma[4], La[4];
        float yy[4] = {2.f * xi.x, 2.f * xi.y, 2.f * xi.z, 2.f * xi.w};
#pragma unroll
        for (int c = 0; c < 4; ++c) {
            u16 h = f2bf(yy[c]);             float fh = bf2f(h);
            u16 m = f2bf(yy[c] - fh);        float fm = bf2f(m);
            u16 l = f2bf(yy[c] - fh - fm);
            Ha[c] = h; Ma[c] = m; La[c] = l;
        }
        const u16 ONEB = 0x3F80;  // bf16 1.0
#pragma unroll
        for (int c = 0; c < 4; ++c) {
            u16 lo, hi;
            if (g == 0)      { lo = Ha[c]; hi = Ha[c]; }  // p0:hi  p1:hi
            else if (g == 1) { lo = Ma[c]; hi = Ha[c]; }  // p2:mid p3:hi
            else if (g == 2) { lo = La[c]; hi = Ma[c]; }  // p4:lo  p5:mid
            else             { lo = (c < 3) ? ONEB : 0; hi = 0; }  // k24..26=1
            qfrag[c]     = (short)lo;
            qfrag[c + 4] = (short)hi;
        }
    }
    const f32x4 zacc = {0.f, 0.f, 0.f, 0.f};
    // candidate fragment (A operand): cand-in-block = lane&15, k-chunk = g
    const bf16x8* bp = (const bf16x8*)bfrag + (size_t)pblk * 64 + (q * 4 + g);

    // ================= Phase A: sampled class-maxima (stride-2 blocks) =====
    f32x4 mx = {-INFINITY, -INFINITY, -INFINITY, -INFINITY};
    for (int t = 0; t < PBLK; t += 8) {    // 64 sampled blocks of the half
        bf16x8 A0[4];
#pragma unroll
        for (int i = 0; i < 4; ++i) A0[i] = bp[(t + 2 * i) * 64];
#pragma unroll
        for (int i = 0; i < 4; ++i) {
            const f32x4 aa = __builtin_amdgcn_mfma_f32_16x16x32_bf16(
                A0[i], qfrag, zacc, 0, 0, 0);
            mx[0] = fmaxf(mx[0], aa[0]); mx[1] = fmaxf(mx[1], aa[1]);
            mx[2] = fmaxf(mx[2], aa[2]); mx[3] = fmaxf(mx[3], aa[3]);
        }
    }

    // ---- combine: 64 class-maxima per query -> tau = 16th largest ----
    // (4 waves x 4 g x 4 reg disjoint classes within this half)
    {
        float* am = (float*)&buf[0][0][0];          // 4 KB scratch alias
        const int base = wave * 256 + q * 16 + g * 4;
        am[base + 0] = mx[0]; am[base + 1] = mx[1];
        am[base + 2] = mx[2]; am[base + 3] = mx[3];
        __syncthreads();
#pragma unroll
        for (int rr = 0; rr < 4; ++rr) {
            const int r = wave * 4 + rr;
            float v = am[(lane >> 4) * 256 + r * 16 + (lane & 15)];
            v = wave_sort_f32(v, lane);
            if (lane == 48) tau_sh[r] = ofsbits(v);  // 16th largest of 64
        }
        __syncthreads();
    }
    float tau = inv_ofs(tau_sh[q]);        // half-tight, fixed for Phase B

    unsigned cq = 0;                        // per-query count (lane-wise,
    uint2* bq = &buf[wave][q][0];           //  replicated across the 4 g-lanes)
    const unsigned gid4 = (unsigned)(g * 4);

// lean lane-wise insert; cold path compacts the overflowing queries
// (ballot/ctz-driven), raising their LOCAL taus.
#define INSERT4(AV, CB) do {                                                 \
    for (;;) {                                                               \
        const bool k0 = (AV)[0] >= tau, k1 = (AV)[1] >= tau;                 \
        const bool k2 = (AV)[2] >= tau, k3 = (AV)[3] >= tau;                 \
        const int cnt = (int)k0 + (int)k1 + (int)k2 + (int)k3;               \
        const int sa = __shfl_xor(cnt, 16, 64);                              \
        const int sb = __shfl_xor(cnt, 32, 64);                              \
        const int sc = __shfl_xor(sa, 32, 64);                               \
        const int tot = cnt + sa + sb + sc;                                  \
        const int pf  = ((g & 1) ? sa : 0) + ((g & 2) ? (sb + sc) : 0);      \
        const u64 ovm = __ballot(cq + (unsigned)tot > CAP);                  \
        if (__builtin_expect(ovm == 0, 1)) {                                 \
            unsigned slot = cq + (unsigned)pf;                               \
            if (k0) bq[slot++] = make_uint2(__float_as_uint((AV)[0]), (CB)); \
            if (k1) bq[slot++] = make_uint2(__float_as_uint((AV)[1]), (CB)+1);\
            if (k2) bq[slot++] = make_uint2(__float_as_uint((AV)[2]), (CB)+2);\
            if (k3) bq[slot++] = make_uint2(__float_as_uint((AV)[3]), (CB)+3);\
            cq += (unsigned)tot;                                             \
            break;                                                           \
        }                                                                    \
        u64 ov = ovm & 0xFFFFull;                                            \
        while (ov) {                                                         \
            const int r = (int)__builtin_ctzll(ov); ov &= ov - 1;            \
            const unsigned cr =                                              \
                (unsigned)__builtin_amdgcn_readlane((int)cq, r);             \
            CompRes res = wave_compact(&buf[wave][r][0], (int)cr, lane);     \
            if (q == r) { cq = (unsigned)res.nc;                             \
                          tau = fmaxf(tau, res.tau); }                       \
        }                                                                    \
    }                                                                        \
} while (0)

    // ================= Phase B: full stream, fixed tau, single-buffer ======
    for (int t = 0; t < PBLK; t += 4) {
        bf16x8 B0[4];
#pragma unroll
        for (int i = 0; i < 4; ++i) B0[i] = bp[(t + i) * 64];
        f32x4 A4_[4];
#pragma unroll
        for (int i = 0; i < 4; ++i)
            A4_[i] = __builtin_amdgcn_mfma_f32_16x16x32_bf16(B0[i], qfrag,
                                                             zacc, 0, 0, 0);
#pragma unroll
        for (int i = 0; i < 4; ++i) {
            const f32x4 av = A4_[i];
            const float m4 = fmaxf(fmaxf(av[0], av[1]), fmaxf(av[2], av[3]));
            if (__ballot(m4 >= tau))
                INSERT4(av, (unsigned)((pblk + t + i) * 16) + gid4);
        }
    }
#undef INSERT4

    // ---- per-part finalize: park top-16 keys (c <= CAP=38 < 64 always) ----
#pragma unroll 1
    for (int r = 0; r < 16; ++r) {
        int c = __builtin_amdgcn_readlane((int)cq, r);
        uint2* br = &buf[wave][r][0];
        if (c <= 16) {                     // typical: park (merge re-sorts)
            if (lane < 16) {
                u64 key = 0;
                if (lane < c) { const uint2 e = br[lane]; key = mkkey(e.x, e.y); }
                *(u64*)&buf[wave][r][lane] = key;
            }
        } else {
            u64 key = 0;                   // sentinel < any real key
            if (lane < c) { const uint2 e = br[lane]; key = mkkey(e.x, e.y); }
            key = wave_sort_u64(key, lane);
            if (lane >= 48)
                *(u64*)&buf[wave][r][lane - 48] = key;  // top-16, slots 0..15
        }
    }

    // ---- in-block merge: 64 keys/query (4 parts x 16) -> half top-16 ----
    __syncthreads();
#pragma unroll
    for (int rr = 0; rr < 4; ++rr) {
        const int r2 = wave * 4 + rr;
        u64 key = *(const u64*)&buf[lane >> 4][r2][lane & 15];
        key = wave_sort_u64(key, lane);
        if (lane >= 48) {
            const int o = (rowbase + r2) * 32 + half * 16 + (lane - 48);
            vals[o] = (unsigned)(key >> 32);       // ofs-transformed value
            idxs[o] = (u16)keyidx(key);            // idx < 16384 fits u16
        }
    }
}

// ---------------- edge-feature MLP: 32->16 merge + gather + hoisted W2 -----
__global__ __launch_bounds__(256, 2) void mlp_kernel(
        const float4* __restrict__ x4,
        const unsigned* __restrict__ vals,
        const u16* __restrict__ idxs,
        const float4* __restrict__ W2f4,
        const float* __restrict__ W1,
        const float* __restrict__ b1,
        const float* __restrict__ b2,
        float* __restrict__ out) {
    __shared__ __align__(16) float4 w2s[16][64];     // 16 KB, h4-major
    __shared__ __align__(16) float  h1s[4][32][68];  // 34 KB, per-wave
    __shared__ __align__(16) float4 xjs[4][32];      // 2 KB, per-wave gather
    const int lane = threadIdx.x & 63;
    const int wave = threadIdx.x >> 6;
    const int kq   = lane >> 4;
    const int gp   = lane & 15;
    const int p0   = (blockIdx.x * 4 + wave) * 2;    // 2 points per wave

    for (int q = threadIdx.x; q < 1024; q += 256)
        w2s[q & 15][q >> 4] = W2f4[q];               // w2s[h4][g]
    __syncthreads();

    float w1r[8];
#pragma unroll
    for (int c = 0; c < 8; ++c) w1r[c] = W1[lane * 8 + c];
    const float b1r = b1[lane];
    float b2r[4];
#pragma unroll
    for (int gq = 0; gq < 4; ++gq) b2r[gq] = b2[gq * 16 + gp];

    // merge the two half-top-16s (exact: same value bits + idx tie-break as
    // the knn-side keys), then gather winners. Each 32-lane group handles
    // one point's 32 candidates; both halves have >=16 real keys so the
    // top-16 are always real.
    {
        const int pp = lane >> 5;                    // 0 or 1
        const int j  = lane & 31;
        const int o  = (p0 + pp) * 32 + j;
        u64 key = ((u64)vals[o] << 32) | (unsigned)(~(unsigned)idxs[o]);
        key = half32_sort_u64(key, lane);
        if ((lane & 31) >= 16) {
            const int nb = (int)((~(unsigned)key) & 0xFFFFu);
            xjs[wave][pp * 16 + ((lane & 31) - 16)] = x4[nb];
        }
    }
    // wave-private LDS + in-wave vmcnt/lgkmcnt ordering: no barrier

    // layer 1 for both points (lane = hidden feature h)
#pragma unroll
    for (int pp = 0; pp < 2; ++pp) {
        const float4 xi = x4[p0 + pp];
        float hb = b1r;
        hb = fmaf(w1r[4] - w1r[0], xi.x, hb);
        hb = fmaf(w1r[5] - w1r[1], xi.y, hb);
        hb = fmaf(w1r[6] - w1r[2], xi.z, hb);
        hb = fmaf(w1r[7] - w1r[3], xi.w, hb);
#pragma unroll
        for (int k = 0; k < K_NBR; ++k) {
            const float4 xj = xjs[wave][pp * 16 + k];
            float h = hb;
            h = fmaf(w1r[0], xj.x, h);
            h = fmaf(w1r[1], xj.y, h);
            h = fmaf(w1r[2], xj.z, h);
            h = fmaf(w1r[3], xj.w, h);
            h1s[wave][pp * 16 + k][lane] = fmaxf(h, 0.0f);
        }
    }

    // layer 2: acc[pp][kk][gq] (packed pairs over h), h4-outer, w4 hoisted
    v2f acc[2][4][4];
#pragma unroll
    for (int pp = 0; pp < 2; ++pp)
#pragma unroll
        for (int kk = 0; kk < 4; ++kk)
#pragma unroll
            for (int gq = 0; gq < 4; ++gq)
                acc[pp][kk][gq] = (v2f){b2r[gq], 0.0f};

#pragma unroll
    for (int h4 = 0; h4 < 16; ++h4) {
        float4 w4[4];
#pragma unroll
        for (int gq = 0; gq < 4; ++gq) w4[gq] = w2s[h4][gq * 16 + gp];
#pragma unroll
        for (int pp = 0; pp < 2; ++pp) {
#pragma unroll
            for (int kk = 0; kk < 4; ++kk) {
                const float4 hv =
                    *(const float4*)&h1s[wave][pp * 16 + kq * 4 + kk][h4 * 4];
#pragma unroll
                for (int gq = 0; gq < 4; ++gq) {
                    acc[pp][kk][gq] = __builtin_elementwise_fma(
                        (v2f){hv.x, hv.y}, (v2f){w4[gq].x, w4[gq].y},
                        acc[pp][kk][gq]);
                    acc[pp][kk][gq] = __builtin_elementwise_fma(
                        (v2f){hv.z, hv.w}, (v2f){w4[gq].z, w4[gq].w},
                        acc[pp][kk][gq]);
                }
            }
        }
    }

#pragma unroll
    for (int pp = 0; pp < 2; ++pp) {
        float s[4];
#pragma unroll
        for (int gq = 0; gq < 4; ++gq) {
            s[gq] = 0.0f;
#pragma unroll
            for (int kk = 0; kk < 4; ++kk) {
                const float v = acc[pp][kk][gq].x + acc[pp][kk][gq].y;
                s[gq] += fmaxf(v, 0.0f);
            }
        }
#pragma unroll
        for (int off = 16; off <= 32; off <<= 1)
#pragma unroll
            for (int gq = 0; gq < 4; ++gq)
                s[gq] += __shfl_xor(s[gq], off, 64);

        out[(p0 + pp) * H_DIM + kq * 16 + gp] = s[kq] * (1.0f / 16.0f);
    }
}

extern "C" void kernel_launch(void* const* d_in, const int* in_sizes, int n_in,
                              void* d_out, int out_size, void* d_ws, size_t ws_size,
                              hipStream_t stream) {
    (void)in_sizes; (void)n_in; (void)out_size; (void)ws_size;
    const float* x  = (const float*)d_in[0];
    const float* W1 = (const float*)d_in[1];
    const float* b1 = (const float*)d_in[2];
    const float* W2 = (const float*)d_in[3];
    const float* b2 = (const float*)d_in[4];
    float* out = (float*)d_out;

    // workspace: [0,1M) bfrag, [1M,3M) vals (u32), [3M,4M) idxs (u16)
    u16*      bfrag = (u16*)d_ws;
    unsigned* vals  = (unsigned*)((char*)d_ws + (1u << 20));
    u16*      idxs  = (u16*)((char*)d_ws + (3u << 20));

    const float4* x4 = (const float4*)x;

    prep_kernel<<<N_PTS / 256, 256, 0, stream>>>(x4, bfrag);
    knn_kernel <<<N_PTS / 16 * 2, 256, 0, stream>>>(x4, bfrag, vals, idxs);
    mlp_kernel <<<N_PTS / 8,   256, 0, stream>>>(
        x4, vals, idxs, (const float4*)W2, W1, b1, b2, out);
}

// Round 13
// 203.940 us; speedup vs baseline: 1.0788x; 1.0564x over previous
//
#include <hip/hip_runtime.h>
#include <math.h>

#define N_PTS 16384
#define K_NBR 16
#define H_DIM 64
#define QPB   32              // queries per block (2 sets of 16)
#define CAP   38              // per-query/per-part buffer; 4*32*CAP*8+128 = 39040
#define NBLK  (N_PTS / 16)    // 1024 column-blocks of 16 candidates
#define HBLK  (NBLK / 2)      // 512 col-blocks per half
#define PBLK  (HBLK / 4)      // 128 col-blocks per wave-part

typedef unsigned long long u64;
typedef unsigned short u16;
typedef float v2f   __attribute__((ext_vector_type(2)));
typedef float f32x4 __attribute__((ext_vector_type(4)));
typedef short bf16x8 __attribute__((ext_vector_type(8)));

// key = (order-preserving float bits, ~idx): sorts by value desc then idx asc
__device__ __forceinline__ u64 mkkey(unsigned vbits, unsigned idx) {
    unsigned of = vbits ^ (unsigned)(((int)vbits >> 31) | 0x80000000);
    return ((u64)of << 32) | (unsigned)(~idx);
}
__device__ __forceinline__ unsigned keyidx(u64 k) { return ~(unsigned)k; }

__device__ __forceinline__ float readlane_f(float v, int l) {
    return __uint_as_float(__builtin_amdgcn_readlane(__float_as_uint(v), l));
}

// order-preserving float<->uint (tau stored in LDS as monotone uint)
__device__ __forceinline__ unsigned ofsbits(float f) {
    unsigned b = __float_as_uint(f);
    return b ^ ((unsigned)((int)b >> 31) | 0x80000000u);
}
__device__ __forceinline__ float inv_ofs(unsigned u) {
    return __uint_as_float(u ^ (~(unsigned)((int)u >> 31) | 0x80000000u));
}

// bf16 RNE helpers (identical arithmetic in prep and knn query-side)
__device__ __forceinline__ u16 f2bf(float f) {
    unsigned u = __float_as_uint(f);
    return (u16)((u + 0x7FFFu + ((u >> 16) & 1u)) >> 16);
}
__device__ __forceinline__ float bf2f(u16 b) {
    return __uint_as_float(((unsigned)b) << 16);
}

// 64-lane bitonic ascending sort, float
__device__ __forceinline__ float wave_sort_f32(float v, int lane) {
#pragma unroll
    for (int k = 2; k <= 64; k <<= 1) {
#pragma unroll
        for (int j = k >> 1; j > 0; j >>= 1) {
            float o = __shfl_xor(v, j, 64);
            bool keep_min = (((lane & k) == 0) == ((lane & j) == 0));
            v = keep_min ? fminf(v, o) : fmaxf(v, o);
        }
    }
    return v;
}
// 64-lane bitonic ascending sort, u64 keys
__device__ __forceinline__ u64 wave_sort_u64(u64 v, int lane) {
#pragma unroll
    for (int k = 2; k <= 64; k <<= 1) {
#pragma unroll
        for (int j = k >> 1; j > 0; j >>= 1) {
            u64 o = __shfl_xor((unsigned long long)v, j, 64);
            bool keep_min = (((lane & k) == 0) == ((lane & j) == 0));
            u64 mn = (v < o) ? v : o;
            u64 mx = (v < o) ? o : v;
            v = keep_min ? mn : mx;
        }
    }
    return v;
}
// two independent 32-lane ascending sorts (halves of the wave); all shfl
// distances <= 16 so lanes never cross the 32-boundary.
__device__ __forceinline__ u64 half32_sort_u64(u64 v, int lane) {
    const int l = lane & 31;
#pragma unroll
    for (int k = 2; k <= 32; k <<= 1) {
#pragma unroll
        for (int j = k >> 1; j > 0; j >>= 1) {
            u64 o = __shfl_xor((unsigned long long)v, j, 64);
            bool keep_min = (((l & k) == 0) == ((l & j) == 0));
            u64 mn = (v < o) ? v : o;
            u64 mx = (v < o) ? o : v;
            v = keep_min ? mn : mx;
        }
    }
    return v;
}

// raise tau to 16th-largest of per-lane max VALUES, drop entries below.
// Exact invariant: tau <= 16th-largest value in buffer (>= 16 entries >= tau
// retained; boundary ties kept).
struct CompRes { int nc; float tau; };
__device__ __attribute__((noinline)) CompRes wave_compact(uint2* buf, int cnt,
                                                          int lane) {
    float lm = -INFINITY;
    for (int s = lane; s < cnt; s += 64)
        lm = fmaxf(lm, __uint_as_float(buf[s].x));
    const float tv = readlane_f(wave_sort_f32(lm, lane), 48);
    int nc = 0;
    for (int s0 = 0; s0 < cnt; s0 += 64) {
        const int s = s0 + lane;
        uint2 e = make_uint2(0u, 0u);
        bool keep = false;
        if (s < cnt) { e = buf[s]; keep = (__uint_as_float(e.x) >= tv); }
        const u64 km = __ballot(keep);
        if (keep) {
            int pfx = (int)__popcll(km & ((1ull << lane) - 1));
            buf[nc + pfx] = e;   // write idx <= read idx: safe
        }
        nc += (int)__popcll(km);
    }
    CompRes r; r.nc = nc; r.tau = tv;
    return r;
}

// query fragment (B operand) for bf16x3-split MFMA, k-chunk = g
__device__ __forceinline__ bf16x8 make_qfrag(float4 xi, int g) {
    u16 Ha[4], Ma[4], La[4];
    float yy[4] = {2.f * xi.x, 2.f * xi.y, 2.f * xi.z, 2.f * xi.w};
#pragma unroll
    for (int c = 0; c < 4; ++c) {
        u16 h = f2bf(yy[c]);             float fh = bf2f(h);
        u16 m = f2bf(yy[c] - fh);        float fm = bf2f(m);
        u16 l = f2bf(yy[c] - fh - fm);
        Ha[c] = h; Ma[c] = m; La[c] = l;
    }
    const u16 ONEB = 0x3F80;  // bf16 1.0
    bf16x8 qf;
#pragma unroll
    for (int c = 0; c < 4; ++c) {
        u16 lo, hi;
        if (g == 0)      { lo = Ha[c]; hi = Ha[c]; }  // p0:hi  p1:hi
        else if (g == 1) { lo = Ma[c]; hi = Ha[c]; }  // p2:mid p3:hi
        else if (g == 2) { lo = La[c]; hi = Ma[c]; }  // p4:lo  p5:mid
        else             { lo = (c < 3) ? ONEB : 0; hi = 0; }  // k24..26=1
        qf[c]     = (short)lo;
        qf[c + 4] = (short)hi;
    }
    return qf;
}

// ---------------- prep: fragment array for bf16x3-split MFMA ---------------
// Score(i,j) = 2*xi.xj - ||xj||^2  (row term -||xi||^2 is rank-invariant).
// K-slot map (k = c + 4p, c=0..3): pairs p:(sa,sb) = (0,0)(0,1)(1,0)(0,2)
// (2,0)(1,1)  [hh,hm,mh,hl,lh,mm of split3]; k=24..26: query-side 1.0,
// cand-side split3(-xx); k=27..31: 0.  Dropped terms (ml,lm,ll) ~2^-27 rel.
__global__ __launch_bounds__(256) void prep_kernel(const float4* __restrict__ x4,
                                                   u16* __restrict__ bf) {
    const int i = blockIdx.x * 256 + threadIdx.x;
    const float4 v = x4[i];
    float xx;
    {
#pragma clang fp contract(off)
        float s0 = v.x * v.x, s1 = v.y * v.y, s2 = v.z * v.z, s3 = v.w * v.w;
        xx = ((s0 + s1) + s2) + s3;
    }
    float c[4] = {v.x, v.y, v.z, v.w};
    u16 H[4], M[4], L[4];
#pragma unroll
    for (int q = 0; q < 4; ++q) {
        float f = c[q];
        u16 h = f2bf(f);            float fh = bf2f(h);
        u16 m = f2bf(f - fh);       float fm = bf2f(m);
        u16 l = f2bf(f - fh - fm);
        H[q] = h; M[q] = m; L[q] = l;
    }
    const float nx = -xx;
    u16 X0 = f2bf(nx);              float x0f = bf2f(X0);
    u16 X1 = f2bf(nx - x0f);        float x1f = bf2f(X1);
    u16 X2 = f2bf(nx - x0f - x1f);
    u16 o[32];
#pragma unroll
    for (int q = 0; q < 4; ++q) {
        o[q]      = H[q];  // p0: sb=hi
        o[4 + q]  = M[q];  // p1: sb=mid
        o[8 + q]  = H[q];  // p2: sb=hi
        o[12 + q] = L[q];  // p3: sb=lo
        o[16 + q] = H[q];  // p4: sb=hi
        o[20 + q] = M[q];  // p5: sb=mid
    }
    o[24] = X0; o[25] = X1; o[26] = X2;
    o[27] = 0; o[28] = 0; o[29] = 0; o[30] = 0; o[31] = 0;
    uint4* dst = (uint4*)(bf + (size_t)i * 32);
#pragma unroll
    for (int q2 = 0; q2 < 4; ++q2) {
        uint4 w;
        w.x = (unsigned)o[q2 * 8 + 0] | ((unsigned)o[q2 * 8 + 1] << 16);
        w.y = (unsigned)o[q2 * 8 + 2] | ((unsigned)o[q2 * 8 + 3] << 16);
        w.z = (unsigned)o[q2 * 8 + 4] | ((unsigned)o[q2 * 8 + 5] << 16);
        w.w = (unsigned)o[q2 * 8 + 6] | ((unsigned)o[q2 * 8 + 7] << 16);
        dst[q2] = w;
    }
}

// ---------------- kNN: two-phase, 2 query-sets per wave (traffic halved) ---
// R12 post-mortem: 73% occupancy via (256,8) spilled (VGPR 32, 25 MB
// scratch) and landed at R7's time -- the >4-waves/SIMD avenue is closed
// (working set ~56-70 unified regs > 64-reg tier). The untouched axis is
// ARITHMETIC INTENSITY: knn streams 1.5 GB from L2 (~45 us floor). This
// version: each wave carries TWO query fragments (32 queries/block), so
// each loaded candidate block feeds 2 MFMA + 2 gates -> L2 traffic halves
// (786 MB, ~23 us floor) and per-load issue work doubles (better latency
// cover at the same proven 4 waves/SIMD). (256,4) -- never bound below
// the proven codegen. LDS 39040 B -> 4 blk/CU; grid 1024 = exactly 4/CU.
// Tau stats identical to R12 (4096-sample of 8192/half, ~8 surv/row).
__global__ __launch_bounds__(256, 4) void knn_kernel(
        const float4* __restrict__ x4,
        const u16* __restrict__ bfrag,
        unsigned* __restrict__ vals,
        u16* __restrict__ idxs) {
    __shared__ __align__(16) uint2 buf[4][QPB][CAP];  // 38912 B
    __shared__ unsigned tau_sh[QPB];                  // +128 B = 39040 B
    const int lane = threadIdx.x & 63;
    const int wave = threadIdx.x >> 6;
    const int q    = lane & 15;
    const int g    = lane >> 4;
    const int qgrp = blockIdx.x >> 1;      // 512 query groups
    const int half = blockIdx.x & 1;
    const int qbase = qgrp * QPB;
    const int pblk = half * HBLK + wave * PBLK;   // part's first 16-col block

    const bf16x8 qf0 = make_qfrag(x4[qbase + q], g);
    const bf16x8 qf1 = make_qfrag(x4[qbase + 16 + q], g);
    const f32x4 zacc = {0.f, 0.f, 0.f, 0.f};
    // candidate fragment (A operand): cand-in-block = lane&15, k-chunk = g
    const bf16x8* bp = (const bf16x8*)bfrag + (size_t)pblk * 64 + (q * 4 + g);

    // ================= Phase A: sampled class-maxima (stride-2 blocks) =====
    f32x4 mx0 = {-INFINITY, -INFINITY, -INFINITY, -INFINITY};
    f32x4 mx1 = mx0;
    for (int t = 0; t < PBLK; t += 8) {    // 64 sampled blocks of the part
        bf16x8 A0[4];
#pragma unroll
        for (int i = 0; i < 4; ++i) A0[i] = bp[(t + 2 * i) * 64];
#pragma unroll
        for (int i = 0; i < 4; ++i) {
            const f32x4 a0 = __builtin_amdgcn_mfma_f32_16x16x32_bf16(
                A0[i], qf0, zacc, 0, 0, 0);
            mx0[0] = fmaxf(mx0[0], a0[0]); mx0[1] = fmaxf(mx0[1], a0[1]);
            mx0[2] = fmaxf(mx0[2], a0[2]); mx0[3] = fmaxf(mx0[3], a0[3]);
            const f32x4 a1 = __builtin_amdgcn_mfma_f32_16x16x32_bf16(
                A0[i], qf1, zacc, 0, 0, 0);
            mx1[0] = fmaxf(mx1[0], a1[0]); mx1[1] = fmaxf(mx1[1], a1[1]);
            mx1[2] = fmaxf(mx1[2], a1[2]); mx1[3] = fmaxf(mx1[3], a1[3]);
        }
    }

    // ---- combine: 64 class-maxima per query -> tau = 16th largest ----
    // class = (wave, g, reg): disjoint candidate sets within the half.
    {
        float* am = (float*)&buf[0][0][0];          // 8 KB scratch alias
        const int col = wave * 16 + g * 4;
#pragma unroll
        for (int j = 0; j < 4; ++j) {
            am[q * 64 + col + j]        = mx0[j];
            am[(16 + q) * 64 + col + j] = mx1[j];
        }
        __syncthreads();
#pragma unroll
        for (int rr = 0; rr < 8; ++rr) {            // wave sorts 8 query rows
            const int r = wave * 8 + rr;
            float v = am[r * 64 + lane];
            v = wave_sort_f32(v, lane);
            if (lane == 48) tau_sh[r] = ofsbits(v); // 16th largest of 64
        }
        __syncthreads();
    }
    float tau0 = inv_ofs(tau_sh[q]);       // half-tight, fixed for Phase B
    float tau1 = inv_ofs(tau_sh[16 + q]);

    unsigned cq0 = 0, cq1 = 0;             // per-query counts (lane-wise)
    uint2* bq0 = &buf[wave][q][0];
    uint2* bq1 = &buf[wave][16 + q][0];
    const unsigned gid4 = (unsigned)(g * 4);

// lean lane-wise insert for query-set S; cold path compacts overflowing
// rows (ballot/ctz-driven), raising their LOCAL taus.
#define INSERT4(AV, CB, TAU, CQ, BQ, ROWOFF) do {                            \
    for (;;) {                                                               \
        const bool k0 = (AV)[0] >= (TAU), k1 = (AV)[1] >= (TAU);             \
        const bool k2 = (AV)[2] >= (TAU), k3 = (AV)[3] >= (TAU);             \
        const int cnt = (int)k0 + (int)k1 + (int)k2 + (int)k3;               \
        const int sa = __shfl_xor(cnt, 16, 64);                              \
        const int sb = __shfl_xor(cnt, 32, 64);                              \
        const int sc = __shfl_xor(sa, 32, 64);                               \
        const int tot = cnt + sa + sb + sc;                                  \
        const int pf  = ((g & 1) ? sa : 0) + ((g & 2) ? (sb + sc) : 0);      \
        const u64 ovm = __ballot((CQ) + (unsigned)tot > CAP);                \
        if (__builtin_expect(ovm == 0, 1)) {                                 \
            unsigned slot = (CQ) + (unsigned)pf;                             \
            if (k0) (BQ)[slot++] = make_uint2(__float_as_uint((AV)[0]), (CB)); \
            if (k1) (BQ)[slot++] = make_uint2(__float_as_uint((AV)[1]), (CB)+1);\
            if (k2) (BQ)[slot++] = make_uint2(__float_as_uint((AV)[2]), (CB)+2);\
            if (k3) (BQ)[slot++] = make_uint2(__float_as_uint((AV)[3]), (CB)+3);\
            (CQ) += (unsigned)tot;                                           \
            break;                                                           \
        }                                                                    \
        u64 ov = ovm & 0xFFFFull;                                            \
        while (ov) {                                                         \
            const int r = (int)__builtin_ctzll(ov); ov &= ov - 1;            \
            const unsigned cr =                                              \
                (unsigned)__builtin_amdgcn_readlane((int)(CQ), r);           \
            CompRes res = wave_compact(&buf[wave][(ROWOFF) + r][0], (int)cr, \
                                       lane);                                \
            if (q == r) { (CQ) = (unsigned)res.nc;                           \
                          (TAU) = fmaxf((TAU), res.tau); }                   \
        }                                                                    \
    }                                                                        \
} while (0)

// one 16x16 cand-block x 2 query-sets: 2 MFMA -> 2 gates -> rare inserts
#define PROC4(BUF, TB) do {                                                  \
    _Pragma("unroll")                                                        \
    for (int i = 0; i < 4; ++i) {                                            \
        const f32x4 a0 = __builtin_amdgcn_mfma_f32_16x16x32_bf16(            \
            BUF[i], qf0, zacc, 0, 0, 0);                                     \
        const f32x4 a1 = __builtin_amdgcn_mfma_f32_16x16x32_bf16(            \
            BUF[i], qf1, zacc, 0, 0, 0);                                     \
        const unsigned cb = (unsigned)(((TB) + i) * 16) + gid4;              \
        const float m0 = fmaxf(fmaxf(a0[0], a0[1]), fmaxf(a0[2], a0[3]));    \
        if (__ballot(m0 >= tau0)) INSERT4(a0, cb, tau0, cq0, bq0, 0);        \
        const float m1 = fmaxf(fmaxf(a1[0], a1[1]), fmaxf(a1[2], a1[3]));    \
        if (__ballot(m1 >= tau1)) INSERT4(a1, cb, tau1, cq1, bq1, 16);       \
    }                                                                        \
} while (0)

    // ================= Phase B: full stream, fixed tau, 2-deep =============
    {
        bf16x8 B0[4], B1[4];
#pragma unroll
        for (int i = 0; i < 4; ++i) B0[i] = bp[i * 64];
#pragma unroll
        for (int i = 0; i < 4; ++i) B1[i] = bp[(4 + i) * 64];
        const bf16x8* pA = bp + 8 * 64;    // refill source for B0 (block t+8)
        const bf16x8* pB = bp + 12 * 64;   // refill source for B1 (block t+12)

        int t = 0;
        for (; t < PBLK - 8; t += 8) {
            PROC4(B0, pblk + t);
#pragma unroll
            for (int i = 0; i < 4; ++i) B0[i] = pA[i * 64];
            pA += 8 * 64;
            PROC4(B1, pblk + t + 4);
#pragma unroll
            for (int i = 0; i < 4; ++i) B1[i] = pB[i * 64];
            pB += 8 * 64;
        }
        PROC4(B0, pblk + t);               // blocks 120..123
        PROC4(B1, pblk + t + 4);           // blocks 124..127
    }
#undef PROC4
#undef INSERT4

    // ---- per-part finalize: park top-16 keys (c <= CAP=38 < 64 always) ----
#pragma unroll 1
    for (int r = 0; r < QPB; ++r) {
        int c = __builtin_amdgcn_readlane((int)((r < 16) ? cq0 : cq1), r & 15);
        uint2* br = &buf[wave][r][0];
        if (c <= 16) {                     // typical: park (merge re-sorts)
            if (lane < 16) {
                u64 key = 0;
                if (lane < c) { const uint2 e = br[lane]; key = mkkey(e.x, e.y); }
                *(u64*)&buf[wave][r][lane] = key;
            }
        } else {
            u64 key = 0;                   // sentinel < any real key
            if (lane < c) { const uint2 e = br[lane]; key = mkkey(e.x, e.y); }
            key = wave_sort_u64(key, lane);
            if (lane >= 48)
                *(u64*)&buf[wave][r][lane - 48] = key;  // top-16, slots 0..15
        }
    }

    // ---- in-block merge: 64 keys/query (4 parts x 16) -> half top-16 ----
    __syncthreads();
#pragma unroll
    for (int rr = 0; rr < 8; ++rr) {
        const int r2 = wave * 8 + rr;
        u64 key = *(const u64*)&buf[lane >> 4][r2][lane & 15];
        key = wave_sort_u64(key, lane);
        if (lane >= 48) {
            const int o = (qbase + r2) * 32 + half * 16 + (lane - 48);
            vals[o] = (unsigned)(key >> 32);       // ofs-transformed value
            idxs[o] = (u16)keyidx(key);            // idx < 16384 fits u16
        }
    }
}

// ---------------- edge-feature MLP: 32->16 merge + gather + hoisted W2 -----
__global__ __launch_bounds__(256, 2) void mlp_kernel(
        const float4* __restrict__ x4,
        const unsigned* __restrict__ vals,
        const u16* __restrict__ idxs,
        const float4* __restrict__ W2f4,
        const float* __restrict__ W1,
        const float* __restrict__ b1,
        const float* __restrict__ b2,
        float* __restrict__ out) {
    __shared__ __align__(16) float4 w2s[16][64];     // 16 KB, h4-major
    __shared__ __align__(16) float  h1s[4][32][68];  // 34 KB, per-wave
    __shared__ __align__(16) float4 xjs[4][32];      // 2 KB, per-wave gather
    const int lane = threadIdx.x & 63;
    const int wave = threadIdx.x >> 6;
    const int kq   = lane >> 4;
    const int gp   = lane & 15;
    const int p0   = (blockIdx.x * 4 + wave) * 2;    // 2 points per wave

    for (int q = threadIdx.x; q < 1024; q += 256)
        w2s[q & 15][q >> 4] = W2f4[q];               // w2s[h4][g]
    __syncthreads();

    float w1r[8];
#pragma unroll
    for (int c = 0; c < 8; ++c) w1r[c] = W1[lane * 8 + c];
    const float b1r = b1[lane];
    float b2r[4];
#pragma unroll
    for (int gq = 0; gq < 4; ++gq) b2r[gq] = b2[gq * 16 + gp];

    // merge the two half-top-16s (exact: same value bits + idx tie-break as
    // the knn-side keys), then gather winners. Each 32-lane group handles
    // one point's 32 candidates; both halves have >=16 real keys so the
    // top-16 are always real.
    {
        const int pp = lane >> 5;                    // 0 or 1
        const int j  = lane & 31;
        const int o  = (p0 + pp) * 32 + j;
        u64 key = ((u64)vals[o] << 32) | (unsigned)(~(unsigned)idxs[o]);
        key = half32_sort_u64(key, lane);
        if ((lane & 31) >= 16) {
            const int nb = (int)((~(unsigned)key) & 0xFFFFu);
            xjs[wave][pp * 16 + ((lane & 31) - 16)] = x4[nb];
        }
    }
    // wave-private LDS + in-wave vmcnt/lgkmcnt ordering: no barrier

    // layer 1 for both points (lane = hidden feature h)
#pragma unroll
    for (int pp = 0; pp < 2; ++pp) {
        const float4 xi = x4[p0 + pp];
        float hb = b1r;
        hb = fmaf(w1r[4] - w1r[0], xi.x, hb);
        hb = fmaf(w1r[5] - w1r[1], xi.y, hb);
        hb = fmaf(w1r[6] - w1r[2], xi.z, hb);
        hb = fmaf(w1r[7] - w1r[3], xi.w, hb);
#pragma unroll
        for (int k = 0; k < K_NBR; ++k) {
            const float4 xj = xjs[wave][pp * 16 + k];
            float h = hb;
            h = fmaf(w1r[0], xj.x, h);
            h = fmaf(w1r[1], xj.y, h);
            h = fmaf(w1r[2], xj.z, h);
            h = fmaf(w1r[3], xj.w, h);
            h1s[wave][pp * 16 + k][lane] = fmaxf(h, 0.0f);
        }
    }

    // layer 2: acc[pp][kk][gq] (packed pairs over h), h4-outer, w4 hoisted
    v2f acc[2][4][4];
#pragma unroll
    for (int pp = 0; pp < 2; ++pp)
#pragma unroll
        for (int kk = 0; kk < 4; ++kk)
#pragma unroll
            for (int gq = 0; gq < 4; ++gq)
                acc[pp][kk][gq] = (v2f){b2r[gq], 0.0f};

#pragma unroll
    for (int h4 = 0; h4 < 16; ++h4) {
        float4 w4[4];
#pragma unroll
        for (int gq = 0; gq < 4; ++gq) w4[gq] = w2s[h4][gq * 16 + gp];
#pragma unroll
        for (int pp = 0; pp < 2; ++pp) {
#pragma unroll
            for (int kk = 0; kk < 4; ++kk) {
                const float4 hv =
                    *(const float4*)&h1s[wave][pp * 16 + kq * 4 + kk][h4 * 4];
#pragma unroll
                for (int gq = 0; gq < 4; ++gq) {
                    acc[pp][kk][gq] = __builtin_elementwise_fma(
                        (v2f){hv.x, hv.y}, (v2f){w4[gq].x, w4[gq].y},
                        acc[pp][kk][gq]);
                    acc[pp][kk][gq] = __builtin_elementwise_fma(
                        (v2f){hv.z, hv.w}, (v2f){w4[gq].z, w4[gq].w},
                        acc[pp][kk][gq]);
                }
            }
        }
    }

#pragma unroll
    for (int pp = 0; pp < 2; ++pp) {
        float s[4];
#pragma unroll
        for (int gq = 0; gq < 4; ++gq) {
            s[gq] = 0.0f;
#pragma unroll
            for (int kk = 0; kk < 4; ++kk) {
                const float v = acc[pp][kk][gq].x + acc[pp][kk][gq].y;
                s[gq] += fmaxf(v, 0.0f);
            }
        }
#pragma unroll
        for (int off = 16; off <= 32; off <<= 1)
#pragma unroll
            for (int gq = 0; gq < 4; ++gq)
                s[gq] += __shfl_xor(s[gq], off, 64);

        out[(p0 + pp) * H_DIM + kq * 16 + gp] = s[kq] * (1.0f / 16.0f);
    }
}

extern "C" void kernel_launch(void* const* d_in, const int* in_sizes, int n_in,
                              void* d_out, int out_size, void* d_ws, size_t ws_size,
                              hipStream_t stream) {
    (void)in_sizes; (void)n_in; (void)out_size; (void)ws_size;
    const float* x  = (const float*)d_in[0];
    const float* W1 = (const float*)d_in[1];
    const float* b1 = (const float*)d_in[2];
    const float* W2 = (const float*)d_in[3];
    const float* b2 = (const float*)d_in[4];
    float* out = (float*)d_out;

    // workspace: [0,1M) bfrag, [1M,3M) vals (u32), [3M,4M) idxs (u16)
    u16*      bfrag = (u16*)d_ws;
    unsigned* vals  = (unsigned*)((char*)d_ws + (1u << 20));
    u16*      idxs  = (u16*)((char*)d_ws + (3u << 20));

    const float4* x4 = (const float4*)x;

    prep_kernel<<<N_PTS / 256, 256, 0, stream>>>(x4, bfrag);
    knn_kernel <<<N_PTS / QPB * 2, 256, 0, stream>>>(x4, bfrag, vals, idxs);
    mlp_kernel <<<N_PTS / 8,   256, 0, stream>>>(
        x4, vals, idxs, (const float4*)W2, W1, b1, b2, out);
}